// Round 14
// baseline (286.771 us; speedup 1.0000x reference)
//
#include <hip/hip_runtime.h>
#include <cstdint>
#include <cstddef>

typedef unsigned short u16;
typedef unsigned int   u32;
typedef __bf16 bf16x8 __attribute__((ext_vector_type(8)));
typedef float  f32x4  __attribute__((ext_vector_type(4)));

#define BS   8192
#define DIMM 512
#define NH   8
#define HD   64
#define SEQ  2048
#define DFF  2048
#define NQKV 1536

// async global->LDS, 16B/lane; LDS dest = wave-uniform base + lane*16
#define GLD16(g, l) __builtin_amdgcn_global_load_lds( \
    (__attribute__((address_space(1))) const void*)(g), \
    (__attribute__((address_space(3))) void*)(l), 16, 0, 0)

__device__ __forceinline__ float b2f(u16 s) {
  u32 u = ((u32)s) << 16;
  float f; __builtin_memcpy(&f, &u, 4); return f;
}
__device__ __forceinline__ u16 f2b(float f) {
  u32 u; __builtin_memcpy(&u, &f, 4);
  u += 0x7fffu + ((u >> 16) & 1u);   // RNE
  return (u16)(u >> 16);
}

// ---- merged weight transpose+convert: 4 weights, one launch ---------------
#define SZ_QKV (DIMM * NQKV)
#define SZ_PRJ (DIMM * DIMM)
#define SZ_F1  (DIMM * DFF)
#define SZ_F2  (DFF * DIMM)
__global__ __launch_bounds__(256) void transpose_all_k(
    const float* __restrict__ w_qkv, const float* __restrict__ w_prj,
    const float* __restrict__ w_f1,  const float* __restrict__ w_f2,
    u16* __restrict__ o_qkv, u16* __restrict__ o_prj,
    u16* __restrict__ o_f1,  u16* __restrict__ o_f2) {
  int idx = blockIdx.x * 256 + threadIdx.x;
  const float* W; u16* O; int Kd, Nd, off;
  if (idx < SZ_QKV)                         { W = w_qkv; O = o_qkv; Kd = DIMM; Nd = NQKV; off = idx; }
  else if (idx < SZ_QKV + SZ_PRJ)           { W = w_prj; O = o_prj; Kd = DIMM; Nd = DIMM; off = idx - SZ_QKV; }
  else if (idx < SZ_QKV + SZ_PRJ + SZ_F1)   { W = w_f1;  O = o_f1;  Kd = DIMM; Nd = DFF;  off = idx - SZ_QKV - SZ_PRJ; }
  else                                      { W = w_f2;  O = o_f2;  Kd = DFF;  Nd = DIMM; off = idx - SZ_QKV - SZ_PRJ - SZ_F1; }
  int n = off / Kd, k = off - n * Kd;
  O[off] = f2b(W[(size_t)k * Nd + n]);
}

// ---------------- LayerNorm f32 -> bf16 (one wave per 512-row) -------------
__global__ __launch_bounds__(256) void ln_f32b_k(const float* __restrict__ X,
    const float* __restrict__ G, const float* __restrict__ Bb, u16* __restrict__ out) {
  int w = threadIdx.x >> 6, lane = threadIdx.x & 63;
  size_t row = (size_t)blockIdx.x * 4 + w;
  const float* xr = X + row * DIMM;
  float v[8];
  *(float4*)&v[0] = *(const float4*)(xr + lane * 8);
  *(float4*)&v[4] = *(const float4*)(xr + lane * 8 + 4);
  float s = 0.f, s2 = 0.f;
#pragma unroll
  for (int j = 0; j < 8; j++) { s += v[j]; s2 += v[j] * v[j]; }
#pragma unroll
  for (int m = 1; m < 64; m <<= 1) { s += __shfl_xor(s, m); s2 += __shfl_xor(s2, m); }
  float mu = s * (1.f / DIMM);
  float rsd = rsqrtf(s2 * (1.f / DIMM) - mu * mu + 1e-5f);
  float g[8], bb[8];
  *(float4*)&g[0]  = *(const float4*)(G + lane * 8);
  *(float4*)&g[4]  = *(const float4*)(G + lane * 8 + 4);
  *(float4*)&bb[0] = *(const float4*)(Bb + lane * 8);
  *(float4*)&bb[4] = *(const float4*)(Bb + lane * 8 + 4);
  uint4 ov; u16* os = (u16*)&ov;
#pragma unroll
  for (int j = 0; j < 8; j++) os[j] = f2b((v[j] - mu) * rsd * g[j] + bb[j]);
  *(uint4*)(out + row * DIMM + lane * 8) = ov;
}

// -------- MFMA GEMM: C[M,N] = A[M,K](bf16) @ BT[N,K](bf16)^T + bias --------
// 2-phase double-buffered pipeline (verified best: R9/R11 bench; T4
// counted-vmcnt REGRESSED ~35us; RoPE-fused epilogue REGRESSED ~15us).
// LDS tiles XOR-swizzled (T2) via pre-swizzled GLOBAL source; read side
// applies the same involution. Measured 0 bank conflicts (R6 counters).
// Macros (not lambdas): R2/R3 toolchain fail.
// EPI 0: f32   EPI 1: f32 (v + f32 resid)   EPI 2: gelu->bf16   EPI 3: bf16
template <int EPI, int TM, int TN, int BK>
__global__ __launch_bounds__(256) void gemm_bt(const u16* __restrict__ A,
    const u16* __restrict__ BT, const float* __restrict__ bias,
    void* __restrict__ Cout, const float* __restrict__ resid, int N, int Kd) {
  constexpr int CPR  = BK / 8;               // 16B chunks per row
  constexpr int CPRB = (BK == 64) ? 3 : 2;
  constexpr int RS   = (BK == 64) ? 0 : 1;   // swizzle: vary per 128B window
  constexpr int KK   = BK / 32;
  constexpr int WROWS = (TN == 128) ? TM / 2 : TM / 4;
  constexpr int MT   = WROWS / 16;
  __shared__ __align__(16) u16 a_s[2][TM * BK];
  __shared__ __align__(16) u16 b_s[2][TN * BK];
  int t = threadIdx.x, lane = t & 63, w = t >> 6;
  int l15 = lane & 15, quad = lane >> 4;
  int gx = gridDim.x;
  int lid = blockIdx.x + gx * blockIdx.y;
  int per = (gx * gridDim.y) >> 3;
  int nid = (lid & 7) * per + (lid >> 3);    // XCD-contiguous remap
  int bx = nid % gx, by = nid / gx;
  int m0 = by * TM, n0 = bx * TN;
  int wm = (TN == 128) ? (w >> 1) * WROWS : w * WROWS;
  int wn = (TN == 128) ? (w & 1) * 64 : 0;
  f32x4 z4 = {0.f, 0.f, 0.f, 0.f};
  f32x4 acc[MT][4];
#pragma unroll
  for (int i = 0; i < MT; i++)
#pragma unroll
    for (int j = 0; j < 4; j++) acc[i][j] = z4;

#define GSTAGE(buf, ts) do {                                                  \
    int k0_ = (ts) * BK;                                                      \
    _Pragma("unroll")                                                         \
    for (int i = 0; i < TM * CPR / 256; i++) {                                \
      int c_ = t + i * 256;                                                   \
      int row_ = c_ >> CPRB, pos_ = c_ & (CPR - 1);                           \
      int ch_ = (pos_ ^ (row_ >> RS)) & (CPR - 1);                            \
      GLD16(A + (size_t)(m0 + row_) * Kd + k0_ + ch_ * 8, &a_s[buf][c_ * 8]); \
    }                                                                         \
    _Pragma("unroll")                                                         \
    for (int i = 0; i < TN * CPR / 256; i++) {                                \
      int c_ = t + i * 256;                                                   \
      int row_ = c_ >> CPRB, pos_ = c_ & (CPR - 1);                           \
      int ch_ = (pos_ ^ (row_ >> RS)) & (CPR - 1);                            \
      GLD16(BT + (size_t)(n0 + row_) * Kd + k0_ + ch_ * 8, &b_s[buf][c_ * 8]);\
    }                                                                         \
  } while (0)

#define GCOMPUTE(buf) do {                                                    \
    bf16x8 af[MT][KK], bfm[4][KK];                                            \
    _Pragma("unroll")                                                         \
    for (int mt = 0; mt < MT; mt++) {                                         \
      _Pragma("unroll")                                                       \
      for (int kk = 0; kk < KK; kk++) {                                       \
        int row_ = wm + mt * 16 + l15;                                        \
        int pos_ = ((kk * 4 + quad) ^ (row_ >> RS)) & (CPR - 1);              \
        af[mt][kk] = *(const bf16x8*)&a_s[buf][row_ * BK + pos_ * 8];         \
      }                                                                       \
    }                                                                         \
    _Pragma("unroll")                                                         \
    for (int nt = 0; nt < 4; nt++) {                                          \
      _Pragma("unroll")                                                       \
      for (int kk = 0; kk < KK; kk++) {                                       \
        int row_ = wn + nt * 16 + l15;                                        \
        int pos_ = ((kk * 4 + quad) ^ (row_ >> RS)) & (CPR - 1);              \
        bfm[nt][kk] = *(const bf16x8*)&b_s[buf][row_ * BK + pos_ * 8];        \
      }                                                                       \
    }                                                                         \
    _Pragma("unroll")                                                         \
    for (int kk = 0; kk < KK; kk++)                                           \
      _Pragma("unroll")                                                       \
      for (int mt = 0; mt < MT; mt++)                                         \
        _Pragma("unroll")                                                     \
        for (int nt = 0; nt < 4; nt++)                                        \
          acc[mt][nt] = __builtin_amdgcn_mfma_f32_16x16x32_bf16(              \
              af[mt][kk], bfm[nt][kk], acc[mt][nt], 0, 0, 0);                 \
  } while (0)

  GSTAGE(0, 0);
  __syncthreads();                 // tile 0 ready (full latency exposed once)
  int nsteps = Kd / BK;            // always even (8/16/32)
  for (int ts = 0; ts < nsteps; ts += 2) {
    GSTAGE(1, ts + 1);             // issue next tile's loads first
    GCOMPUTE(0);
    __syncthreads();               // implicit vmcnt(0) AFTER compute
    if (ts + 2 < nsteps) GSTAGE(0, ts + 2);
    GCOMPUTE(1);
    __syncthreads();
  }
#undef GSTAGE
#undef GCOMPUTE

#pragma unroll
  for (int nt = 0; nt < 4; nt++) {
    int col = n0 + wn + nt * 16 + l15;
    float bv = bias[col];
#pragma unroll
    for (int mt = 0; mt < MT; mt++) {
#pragma unroll
      for (int r = 0; r < 4; r++) {
        int rw = m0 + wm + mt * 16 + quad * 4 + r;
        float v = acc[mt][nt][r] + bv;
        size_t off = (size_t)rw * N + col;
        if (EPI == 0) {
          ((float*)Cout)[off] = v;
        } else if (EPI == 1) {
          ((float*)Cout)[off] = v + resid[off];
        } else if (EPI == 2) {
          ((u16*)Cout)[off] = f2b(0.5f * v * (1.f + erff(v * 0.70710678118654752f)));
        } else {
          ((u16*)Cout)[off] = f2b(v);
        }
      }
    }
  }
}

// ------- RoPE + reorg qkv[BS][1536] bf16 -> Q,K,V [B*H][S][HD] bf16 --------
// Q pre-scaled by (1/sqrt(HD)) * log2(e) so attention can use exp2.
#define QSCALE 0.18033688f
__global__ __launch_bounds__(256) void rope_k(const u16* __restrict__ qkv,
    const float* __restrict__ C, const float* __restrict__ Sn,
    u16* __restrict__ Qo, u16* __restrict__ Ko, u16* __restrict__ Vo) {
  int idx = blockIdx.x * 256 + threadIdx.x;   // one 8-elem chunk
  int row = idx / 192;                        // (b*SEQ + s)
  int cn = idx - row * 192;
  int n0 = cn * 8;
  int comp = n0 >> 9;
  int hh = (n0 >> 6) & 7;
  int d0 = n0 & 63;
  int b = row >> 11, s = row & 2047;
  const u16* src = qkv + (size_t)row * NQKV;
  uint4 val = *(const uint4*)(src + n0);
  u16* vs = (u16*)&val;
  size_t oo = ((size_t)((b << 3) + hh) * SEQ + s) * HD + d0;
  if (comp == 2) { *(uint4*)(Vo + oo) = val; return; }
  uint4 pv = *(const uint4*)(src + (n0 ^ 32));        // rotate-half partner
  u16* ps = (u16*)&pv;
  float cv[8], sv[8];
  *(float4*)&cv[0] = *(const float4*)(C + s * HD + d0);
  *(float4*)&cv[4] = *(const float4*)(C + s * HD + d0 + 4);
  *(float4*)&sv[0] = *(const float4*)(Sn + s * HD + d0);
  *(float4*)&sv[4] = *(const float4*)(Sn + s * HD + d0 + 4);
  float sgn = (d0 & 32) ? 1.f : -1.f;
  float sc = (comp == 0) ? QSCALE : 1.f;
  uint4 ov; u16* os = (u16*)&ov;
#pragma unroll
  for (int j = 0; j < 8; j++)
    os[j] = f2b(sc * (b2f(vs[j]) * cv[j] + sgn * b2f(ps[j]) * sv[j]));
  *(uint4*)((comp == 0 ? Qo : Ko) + oo) = ov;
}

// ------------- V transpose: [bh][s][d] -> Vt [bh][d][s'] (bf16) ------------
// Key order PERMUTED within each 64-key block so attn's PV B-operand maps
// lane-local P registers with ZERO cross-lane exchange:
//   store key s (bits s5..s0) at c = {s5, s3, s2, s4, s1, s0}.
__global__ __launch_bounds__(256) void vtrans_k(const u16* __restrict__ V,
                                                u16* __restrict__ Vt) {
  __shared__ u16 ld[64 * 72];
  int t = threadIdx.x;
  int bh = blockIdx.x >> 5;          // 32 s-tiles per bh
  int s0 = (blockIdx.x & 31) * 64;
  const u16* src = V + (size_t)bh * SEQ * HD + (size_t)s0 * HD;
  u16* dst = Vt + (size_t)bh * SEQ * HD;
#pragma unroll
  for (int i = 0; i < 2; i++) {
    int c = t + i * 256, s = c >> 3, cp = c & 7;
    *(uint4*)&ld[s * 72 + ((cp ^ (s >> 3)) << 3)] =
        *(const uint4*)(src + (size_t)s * HD + cp * 8);
  }
  __syncthreads();
#pragma unroll
  for (int i = 0; i < 2; i++) {
    int c = t + i * 256, d = c >> 3, sc = c & 7;   // sc = s5s4s3 of local key
    u16 os[8];
#pragma unroll
    for (int j = 0; j < 8; j++) {
      int s = sc * 8 + j;
      os[j] = ld[s * 72 + (((d >> 3) ^ (s >> 3)) << 3) + (d & 7)];
    }
    // c(s) = 32*s5 + 16*s3 + 8*s2 + 4*s4 + s1s0
    int cb = ((sc >> 2) << 5) + ((sc & 1) << 4) + (((sc >> 1) & 1) << 2);
    *(uint2*)(dst + (size_t)d * SEQ + s0 + cb)     = *(const uint2*)&os[0];
    *(uint2*)(dst + (size_t)d * SEQ + s0 + cb + 8) = *(const uint2*)&os[4];
  }
}

// ------------ flash attention, swapped-QK in-register softmax --------------
// 8 waves, 128-row q tile, K/V LDS double-buffered (1 barrier/tile),
// lane-local softmax (P feeds PV directly; key perm pre-baked into Vt).
// R13: LDS pitch 72 -> 64 with chunk-XOR swizzle (T2, same as GEMM which
// measures ZERO conflicts): row base = bank 0 for every row; chunk c of
// row r stored at slot c^(r&7). Same XOR on staging writes and fragment
// reads (both plain ds ops -> both-sides rule satisfied). Targets the
// remaining 8.42M SQ_LDS_BANK_CONFLICT (pitch-72 rows 8 apart shared a
// bank-quad on every b128 access).
__global__ __launch_bounds__(512) void attn_flash_k(const u16* __restrict__ Qg,
    const u16* __restrict__ Kg, const u16* __restrict__ Vtg, u16* __restrict__ Og) {
  __shared__ __align__(16) u16 q_s[128 * 64];     // Q staging (XOR-swizzled)
  __shared__ __align__(16) u16 k_s[2][64 * 64];   // K rows, double-buffered
  __shared__ __align__(16) u16 vt_s[2][64 * 64];  // V^T rows (key-permuted)
  int t = threadIdx.x, lane = t & 63, w = t >> 6;   // w in 0..7
  int l15 = lane & 15, quad = lane >> 4;
  int lid = blockIdx.x;                      // 512 blocks
  int nid = (lid & 7) * 64 + (lid >> 3);     // XCD-contiguous remap
  int bh = nid >> 4;                         // 16 q-tiles per (b,h)
  int qt0 = (nid & 15) * 128;
  int b = bh >> 3, h = bh & 7;
  const u16* Qp = Qg + (size_t)bh * SEQ * HD;
  const u16* Kp = Kg + (size_t)bh * SEQ * HD;
  const u16* Vp = Vtg + (size_t)bh * SEQ * HD;   // [d][s'] permuted
  int row = t >> 3, ch = t & 7;    // staging: K -> row=key, V^T -> row=d
  int schu = (ch ^ (row & 7)) << 3;            // swizzled staging slot
  int r7 = l15 & 7;                            // read-side row bits

  // stage Q tile (128 rows, swizzled)
#pragma unroll
  for (int i = 0; i < 2; i++) {
    int c = t + i * 512, qr = c >> 3, qc = c & 7;
    *(uint4*)&q_s[qr * 64 + ((qc ^ (qr & 7)) << 3)] =
        *(const uint4*)(Qp + (size_t)(qt0 + qr) * HD + qc * 8);
  }
  // stage K/V tile 0 into buf0, issue tile 1 loads
  uint4 kr = *(const uint4*)(Kp + (size_t)row * HD + ch * 8);
  uint4 vr = *(const uint4*)(Vp + (size_t)row * SEQ + ch * 8);
  *(uint4*)&k_s[0][row * 64 + schu] = kr;
  *(uint4*)&vt_s[0][row * 64 + schu] = vr;
  kr = *(const uint4*)(Kp + (size_t)(64 + row) * HD + ch * 8);
  vr = *(const uint4*)(Vp + (size_t)row * SEQ + 64 + ch * 8);
  __syncthreads();                 // Q + tile0 visible
  bf16x8 qa[2];
  qa[0] = *(const bf16x8*)&q_s[(w * 16 + l15) * 64 + ((quad ^ r7) << 3)];
  qa[1] = *(const bf16x8*)&q_s[(w * 16 + l15) * 64 + (((4 + quad) ^ r7) << 3)];
  f32x4 z4 = {0.f, 0.f, 0.f, 0.f};
  f32x4 of[4];                     // of[nd][r] = O^T[d=nd*16+quad*4+r][q]
#pragma unroll
  for (int n = 0; n < 4; n++) of[n] = z4;
  float lrun = 0.f;                // one query per lane -> scalar sum

  for (int kt = 0; kt < SEQ; kt += 64) {
    int cur = (kt >> 6) & 1;
    // S^T = mfma(K, Q): sf[n][r] = S[q=w*16+l15][key=n*16+quad*4+r]
    f32x4 sf[4];
#pragma unroll
    for (int n = 0; n < 4; n++) sf[n] = z4;
    __builtin_amdgcn_s_setprio(1);
#pragma unroll
    for (int kk = 0; kk < 2; kk++)
#pragma unroll
      for (int n = 0; n < 4; n++) {
        bf16x8 kb = *(const bf16x8*)&k_s[cur][(n * 16 + l15) * 64 +
                                             (((kk * 4 + quad) ^ r7) << 3)];
        sf[n] = __builtin_amdgcn_mfma_f32_16x16x32_bf16(kb, qa[kk], sf[n], 0, 0, 0);
      }
    __builtin_amdgcn_s_setprio(0);
    // lane-local softmax: exp2 (Q carried log2e/8), pack bf16 pairs in-reg
    u32 p32[4][2];
#pragma unroll
    for (int n = 0; n < 4; n++) {
      float e0 = exp2f(sf[n][0]), e1 = exp2f(sf[n][1]);
      float e2 = exp2f(sf[n][2]), e3 = exp2f(sf[n][3]);
      lrun += (e0 + e1) + (e2 + e3);
      asm("v_cvt_pk_bf16_f32 %0, %1, %2" : "=v"(p32[n][0]) : "v"(e0), "v"(e1));
      asm("v_cvt_pk_bf16_f32 %0, %1, %2" : "=v"(p32[n][1]) : "v"(e2), "v"(e3));
    }
    // O^T += V^T P^T: pbv is lane-local (key order pre-baked into Vt)
    __builtin_amdgcn_s_setprio(1);
#pragma unroll
    for (int kk = 0; kk < 2; kk++) {
      u32 pb[4] = {p32[kk * 2][0], p32[kk * 2][1], p32[kk * 2 + 1][0], p32[kk * 2 + 1][1]};
      bf16x8 pbv;
      __builtin_memcpy(&pbv, pb, 16);
#pragma unroll
      for (int nd = 0; nd < 4; nd++) {
        bf16x8 va = *(const bf16x8*)&vt_s[cur][(nd * 16 + l15) * 64 +
                                              (((kk * 4 + quad) ^ r7) << 3)];
        of[nd] = __builtin_amdgcn_mfma_f32_16x16x32_bf16(va, pbv, of[nd], 0, 0, 0);
      }
    }
    __builtin_amdgcn_s_setprio(0);
    // stage next tile into buf[cur^1]; issue tile kt+128 loads
    if (kt + 64 < SEQ) {
      *(uint4*)&k_s[cur ^ 1][row * 64 + schu] = kr;
      *(uint4*)&vt_s[cur ^ 1][row * 64 + schu] = vr;
      if (kt + 128 < SEQ) {
        kr = *(const uint4*)(Kp + (size_t)(kt + 128 + row) * HD + ch * 8);
        vr = *(const uint4*)(Vp + (size_t)row * SEQ + kt + 128 + ch * 8);
      }
    }
    __syncthreads();               // single barrier per tile
  }
  // norm: lane's partial covers its quad's keys; sum across quads (xor 16,32)
  float l = lrun;
  l += __shfl_xor(l, 16);
  l += __shfl_xor(l, 32);
  float inv = 1.f / l;
  size_t orow = (size_t)(b * SEQ + qt0 + w * 16 + l15);
#pragma unroll
  for (int nd = 0; nd < 4; nd++) {
    uint2 uv;
    uv.x = (u32)f2b(of[nd][0] * inv) | ((u32)f2b(of[nd][1] * inv) << 16);
    uv.y = (u32)f2b(of[nd][2] * inv) | ((u32)f2b(of[nd][3] * inv) << 16);
    *(uint2*)&Og[orow * DIMM + h * HD + nd * 16 + quad * 4] = uv;
  }
}

// ---------------------------------------------------------------------------
extern "C" void kernel_launch(void* const* d_in, const int* in_sizes, int n_in,
                              void* d_out, int out_size, void* d_ws, size_t ws_size,
                              hipStream_t stream) {
  const float* x    = (const float*)d_in[0];
  const float* rc   = (const float*)d_in[1];
  const float* rsn  = (const float*)d_in[2];
  const float* n1g  = (const float*)d_in[3];
  const float* n1b  = (const float*)d_in[4];
  const float* n2g  = (const float*)d_in[5];
  const float* n2b  = (const float*)d_in[6];
  const float* wqkv = (const float*)d_in[7];
  const float* bqkv = (const float*)d_in[8];
  const float* wprj = (const float*)d_in[9];
  const float* bprj = (const float*)d_in[10];
  const float* wf1  = (const float*)d_in[11];
  const float* bf1  = (const float*)d_in[12];
  const float* wf2  = (const float*)d_in[13];
  const float* bf2  = (const float*)d_in[14];

  char* p = (char*)d_ws;
  u16*   wqkvT = (u16*)p;                   // 1.5 MB
  u16*   wprjT = (u16*)(p + (2u  << 20));   // 0.5 MB
  u16*   wf1T  = (u16*)(p + (3u  << 20));   // 2 MB
  u16*   wf2T  = (u16*)(p + (5u  << 20));   // 2 MB
  u16*   h1    = (u16*)(p + (8u  << 20));   // 8 MB bf16: LN1 out / ob / h2
  u16*   qkvb  = (u16*)(p + (16u << 20));   // 24 MB bf16
  u16*   Vt    = (u16*)(p + (40u << 20));   // 8 MB bf16 (dead before FC1's mid)
  u16*   Qb    = (u16*)(p + (64u << 20));   // 8 MB bf16
  u16*   Kb    = (u16*)(p + (72u << 20));   // 8 MB bf16
  u16*   Vb    = (u16*)(p + (80u << 20));   // 8 MB bf16
  float* x2    = (float*)(p + (88u << 20)); // 16 MB f32 residual stream
  u16*   ob    = h1;                        // h1 dead after QKV gemm
  u16*   h2    = h1;                        // ob dead after proj gemm
  u16*   mid   = qkvb;                      // 32 MB bf16 region (qkvb+Vt dead)

  transpose_all_k<<<dim3((SZ_QKV + SZ_PRJ + SZ_F1 + SZ_F2) / 256), 256, 0, stream>>>(
      wqkv, wprj, wf1, wf2, wqkvT, wprjT, wf1T, wf2T);

  ln_f32b_k<<<dim3(BS / 4), 256, 0, stream>>>(x, n1g, n1b, h1);

  gemm_bt<3, 64, 128, 32><<<dim3(NQKV / 128, BS / 64), 256, 0, stream>>>(h1, wqkvT, bqkv, qkvb, nullptr, NQKV, DIMM);

  rope_k<<<dim3(BS * NQKV / 8 / 256), 256, 0, stream>>>(qkvb, rc, rsn, Qb, Kb, Vb);

  vtrans_k<<<dim3(32 * (SEQ / 64)), 256, 0, stream>>>(Vb, Vt);

  attn_flash_k<<<dim3(32 * (SEQ / 128)), 512, 0, stream>>>(Qb, Kb, Vt, ob);

  gemm_bt<1, 64, 64, 64><<<dim3(DIMM / 64, BS / 64), 256, 0, stream>>>(ob, wprjT, bprj, x2, x, DIMM, DIMM);

  ln_f32b_k<<<dim3(BS / 4), 256, 0, stream>>>(x2, n2g, n2b, h2);

  gemm_bt<2, 64, 128, 32><<<dim3(DFF / 128, BS / 64), 256, 0, stream>>>(h2, wf1T, bf1, mid, nullptr, DFF, DIMM);

  gemm_bt<1, 64, 64, 64><<<dim3(DIMM / 64, BS / 64), 256, 0, stream>>>(mid, wf2T, bf2, (float*)d_out, x2, DIMM, DFF);
}

// Round 15
// 285.587 us; speedup vs baseline: 1.0041x; 1.0041x over previous
//
#include <hip/hip_runtime.h>
#include <cstdint>
#include <cstddef>

typedef unsigned short u16;
typedef unsigned int   u32;
typedef __bf16 bf16x8 __attribute__((ext_vector_type(8)));
typedef float  f32x4  __attribute__((ext_vector_type(4)));

#define BS   8192
#define DIMM 512
#define NH   8
#define HD   64
#define SEQ  2048
#define DFF  2048
#define NQKV 1536

// async global->LDS, 16B/lane; LDS dest = wave-uniform base + lane*16
#define GLD16(g, l) __builtin_amdgcn_global_load_lds( \
    (__attribute__((address_space(1))) const void*)(g), \
    (__attribute__((address_space(3))) void*)(l), 16, 0, 0)

__device__ __forceinline__ float b2f(u16 s) {
  u32 u = ((u32)s) << 16;
  float f; __builtin_memcpy(&f, &u, 4); return f;
}
__device__ __forceinline__ u16 f2b(float f) {
  u32 u; __builtin_memcpy(&u, &f, 4);
  u += 0x7fffu + ((u >> 16) & 1u);   // RNE
  return (u16)(u >> 16);
}

// ---- merged weight transpose+convert: 4 weights, one launch ---------------
#define SZ_QKV (DIMM * NQKV)
#define SZ_PRJ (DIMM * DIMM)
#define SZ_F1  (DIMM * DFF)
#define SZ_F2  (DFF * DIMM)
__global__ __launch_bounds__(256) void transpose_all_k(
    const float* __restrict__ w_qkv, const float* __restrict__ w_prj,
    const float* __restrict__ w_f1,  const float* __restrict__ w_f2,
    u16* __restrict__ o_qkv, u16* __restrict__ o_prj,
    u16* __restrict__ o_f1,  u16* __restrict__ o_f2) {
  int idx = blockIdx.x * 256 + threadIdx.x;
  const float* W; u16* O; int Kd, Nd, off;
  if (idx < SZ_QKV)                         { W = w_qkv; O = o_qkv; Kd = DIMM; Nd = NQKV; off = idx; }
  else if (idx < SZ_QKV + SZ_PRJ)           { W = w_prj; O = o_prj; Kd = DIMM; Nd = DIMM; off = idx - SZ_QKV; }
  else if (idx < SZ_QKV + SZ_PRJ + SZ_F1)   { W = w_f1;  O = o_f1;  Kd = DIMM; Nd = DFF;  off = idx - SZ_QKV - SZ_PRJ; }
  else                                      { W = w_f2;  O = o_f2;  Kd = DFF;  Nd = DIMM; off = idx - SZ_QKV - SZ_PRJ - SZ_F1; }
  int n = off / Kd, k = off - n * Kd;
  O[off] = f2b(W[(size_t)k * Nd + n]);
}

// ---------------- LayerNorm f32 -> bf16 (one wave per 512-row) -------------
__global__ __launch_bounds__(256) void ln_f32b_k(const float* __restrict__ X,
    const float* __restrict__ G, const float* __restrict__ Bb, u16* __restrict__ out) {
  int w = threadIdx.x >> 6, lane = threadIdx.x & 63;
  size_t row = (size_t)blockIdx.x * 4 + w;
  const float* xr = X + row * DIMM;
  float v[8];
  *(float4*)&v[0] = *(const float4*)(xr + lane * 8);
  *(float4*)&v[4] = *(const float4*)(xr + lane * 8 + 4);
  float s = 0.f, s2 = 0.f;
#pragma unroll
  for (int j = 0; j < 8; j++) { s += v[j]; s2 += v[j] * v[j]; }
#pragma unroll
  for (int m = 1; m < 64; m <<= 1) { s += __shfl_xor(s, m); s2 += __shfl_xor(s2, m); }
  float mu = s * (1.f / DIMM);
  float rsd = rsqrtf(s2 * (1.f / DIMM) - mu * mu + 1e-5f);
  float g[8], bb[8];
  *(float4*)&g[0]  = *(const float4*)(G + lane * 8);
  *(float4*)&g[4]  = *(const float4*)(G + lane * 8 + 4);
  *(float4*)&bb[0] = *(const float4*)(Bb + lane * 8);
  *(float4*)&bb[4] = *(const float4*)(Bb + lane * 8 + 4);
  uint4 ov; u16* os = (u16*)&ov;
#pragma unroll
  for (int j = 0; j < 8; j++) os[j] = f2b((v[j] - mu) * rsd * g[j] + bb[j]);
  *(uint4*)(out + row * DIMM + lane * 8) = ov;
}

// -------- MFMA GEMM: C[M,N] = A[M,K](bf16) @ BT[N,K](bf16)^T + bias --------
// 2-phase double-buffered pipeline (verified best: R9/R11 bench; T4
// counted-vmcnt REGRESSED ~35us; RoPE-fused epilogue REGRESSED ~15us).
// LDS tiles XOR-swizzled (T2) via pre-swizzled GLOBAL source; read side
// applies the same involution. Measured 0 bank conflicts (R6 counters).
// Macros (not lambdas): R2/R3 toolchain fail.
// EPI 0: f32   EPI 1: f32 (v + f32 resid)   EPI 2: gelu->bf16   EPI 3: bf16
template <int EPI, int TM, int TN, int BK>
__global__ __launch_bounds__(256) void gemm_bt(const u16* __restrict__ A,
    const u16* __restrict__ BT, const float* __restrict__ bias,
    void* __restrict__ Cout, const float* __restrict__ resid, int N, int Kd) {
  constexpr int CPR  = BK / 8;               // 16B chunks per row
  constexpr int CPRB = (BK == 64) ? 3 : 2;
  constexpr int RS   = (BK == 64) ? 0 : 1;   // swizzle: vary per 128B window
  constexpr int KK   = BK / 32;
  constexpr int WROWS = (TN == 128) ? TM / 2 : TM / 4;
  constexpr int MT   = WROWS / 16;
  __shared__ __align__(16) u16 a_s[2][TM * BK];
  __shared__ __align__(16) u16 b_s[2][TN * BK];
  int t = threadIdx.x, lane = t & 63, w = t >> 6;
  int l15 = lane & 15, quad = lane >> 4;
  int gx = gridDim.x;
  int lid = blockIdx.x + gx * blockIdx.y;
  int per = (gx * gridDim.y) >> 3;
  int nid = (lid & 7) * per + (lid >> 3);    // XCD-contiguous remap
  int bx = nid % gx, by = nid / gx;
  int m0 = by * TM, n0 = bx * TN;
  int wm = (TN == 128) ? (w >> 1) * WROWS : w * WROWS;
  int wn = (TN == 128) ? (w & 1) * 64 : 0;
  f32x4 z4 = {0.f, 0.f, 0.f, 0.f};
  f32x4 acc[MT][4];
#pragma unroll
  for (int i = 0; i < MT; i++)
#pragma unroll
    for (int j = 0; j < 4; j++) acc[i][j] = z4;

#define GSTAGE(buf, ts) do {                                                  \
    int k0_ = (ts) * BK;                                                      \
    _Pragma("unroll")                                                         \
    for (int i = 0; i < TM * CPR / 256; i++) {                                \
      int c_ = t + i * 256;                                                   \
      int row_ = c_ >> CPRB, pos_ = c_ & (CPR - 1);                           \
      int ch_ = (pos_ ^ (row_ >> RS)) & (CPR - 1);                            \
      GLD16(A + (size_t)(m0 + row_) * Kd + k0_ + ch_ * 8, &a_s[buf][c_ * 8]); \
    }                                                                         \
    _Pragma("unroll")                                                         \
    for (int i = 0; i < TN * CPR / 256; i++) {                                \
      int c_ = t + i * 256;                                                   \
      int row_ = c_ >> CPRB, pos_ = c_ & (CPR - 1);                           \
      int ch_ = (pos_ ^ (row_ >> RS)) & (CPR - 1);                            \
      GLD16(BT + (size_t)(n0 + row_) * Kd + k0_ + ch_ * 8, &b_s[buf][c_ * 8]);\
    }                                                                         \
  } while (0)

#define GCOMPUTE(buf) do {                                                    \
    bf16x8 af[MT][KK], bfm[4][KK];                                            \
    _Pragma("unroll")                                                         \
    for (int mt = 0; mt < MT; mt++) {                                         \
      _Pragma("unroll")                                                       \
      for (int kk = 0; kk < KK; kk++) {                                       \
        int row_ = wm + mt * 16 + l15;                                        \
        int pos_ = ((kk * 4 + quad) ^ (row_ >> RS)) & (CPR - 1);              \
        af[mt][kk] = *(const bf16x8*)&a_s[buf][row_ * BK + pos_ * 8];         \
      }                                                                       \
    }                                                                         \
    _Pragma("unroll")                                                         \
    for (int nt = 0; nt < 4; nt++) {                                          \
      _Pragma("unroll")                                                       \
      for (int kk = 0; kk < KK; kk++) {                                       \
        int row_ = wn + nt * 16 + l15;                                        \
        int pos_ = ((kk * 4 + quad) ^ (row_ >> RS)) & (CPR - 1);              \
        bfm[nt][kk] = *(const bf16x8*)&b_s[buf][row_ * BK + pos_ * 8];        \
      }                                                                       \
    }                                                                         \
    _Pragma("unroll")                                                         \
    for (int kk = 0; kk < KK; kk++)                                           \
      _Pragma("unroll")                                                       \
      for (int mt = 0; mt < MT; mt++)                                         \
        _Pragma("unroll")                                                     \
        for (int nt = 0; nt < 4; nt++)                                        \
          acc[mt][nt] = __builtin_amdgcn_mfma_f32_16x16x32_bf16(              \
              af[mt][kk], bfm[nt][kk], acc[mt][nt], 0, 0, 0);                 \
  } while (0)

  GSTAGE(0, 0);
  __syncthreads();                 // tile 0 ready (full latency exposed once)
  int nsteps = Kd / BK;            // always even (8/16/32)
  for (int ts = 0; ts < nsteps; ts += 2) {
    GSTAGE(1, ts + 1);             // issue next tile's loads first
    GCOMPUTE(0);
    __syncthreads();               // implicit vmcnt(0) AFTER compute
    if (ts + 2 < nsteps) GSTAGE(0, ts + 2);
    GCOMPUTE(1);
    __syncthreads();
  }
#undef GSTAGE
#undef GCOMPUTE

#pragma unroll
  for (int nt = 0; nt < 4; nt++) {
    int col = n0 + wn + nt * 16 + l15;
    float bv = bias[col];
#pragma unroll
    for (int mt = 0; mt < MT; mt++) {
#pragma unroll
      for (int r = 0; r < 4; r++) {
        int rw = m0 + wm + mt * 16 + quad * 4 + r;
        float v = acc[mt][nt][r] + bv;
        size_t off = (size_t)rw * N + col;
        if (EPI == 0) {
          ((float*)Cout)[off] = v;
        } else if (EPI == 1) {
          ((float*)Cout)[off] = v + resid[off];
        } else if (EPI == 2) {
          ((u16*)Cout)[off] = f2b(0.5f * v * (1.f + erff(v * 0.70710678118654752f)));
        } else {
          ((u16*)Cout)[off] = f2b(v);
        }
      }
    }
  }
}

// ------- RoPE + reorg qkv[BS][1536] bf16 -> Q,K,V [B*H][S][HD] bf16 --------
// Q pre-scaled by (1/sqrt(HD)) * log2(e) so attention can use exp2.
#define QSCALE 0.18033688f
__global__ __launch_bounds__(256) void rope_k(const u16* __restrict__ qkv,
    const float* __restrict__ C, const float* __restrict__ Sn,
    u16* __restrict__ Qo, u16* __restrict__ Ko, u16* __restrict__ Vo) {
  int idx = blockIdx.x * 256 + threadIdx.x;   // one 8-elem chunk
  int row = idx / 192;                        // (b*SEQ + s)
  int cn = idx - row * 192;
  int n0 = cn * 8;
  int comp = n0 >> 9;
  int hh = (n0 >> 6) & 7;
  int d0 = n0 & 63;
  int b = row >> 11, s = row & 2047;
  const u16* src = qkv + (size_t)row * NQKV;
  uint4 val = *(const uint4*)(src + n0);
  u16* vs = (u16*)&val;
  size_t oo = ((size_t)((b << 3) + hh) * SEQ + s) * HD + d0;
  if (comp == 2) { *(uint4*)(Vo + oo) = val; return; }
  uint4 pv = *(const uint4*)(src + (n0 ^ 32));        // rotate-half partner
  u16* ps = (u16*)&pv;
  float cv[8], sv[8];
  *(float4*)&cv[0] = *(const float4*)(C + s * HD + d0);
  *(float4*)&cv[4] = *(const float4*)(C + s * HD + d0 + 4);
  *(float4*)&sv[0] = *(const float4*)(Sn + s * HD + d0);
  *(float4*)&sv[4] = *(const float4*)(Sn + s * HD + d0 + 4);
  float sgn = (d0 & 32) ? 1.f : -1.f;
  float sc = (comp == 0) ? QSCALE : 1.f;
  uint4 ov; u16* os = (u16*)&ov;
#pragma unroll
  for (int j = 0; j < 8; j++)
    os[j] = f2b(sc * (b2f(vs[j]) * cv[j] + sgn * b2f(ps[j]) * sv[j]));
  *(uint4*)((comp == 0 ? Qo : Ko) + oo) = ov;
}

// ------------- V transpose: [bh][s][d] -> Vt [bh][d][s'] (bf16) ------------
// Key order PERMUTED within each 64-key block so attn's PV B-operand maps
// lane-local P registers with ZERO cross-lane exchange:
//   store key s (bits s5..s0) at c = {s5, s3, s2, s4, s1, s0}.
__global__ __launch_bounds__(256) void vtrans_k(const u16* __restrict__ V,
                                                u16* __restrict__ Vt) {
  __shared__ u16 ld[64 * 72];
  int t = threadIdx.x;
  int bh = blockIdx.x >> 5;          // 32 s-tiles per bh
  int s0 = (blockIdx.x & 31) * 64;
  const u16* src = V + (size_t)bh * SEQ * HD + (size_t)s0 * HD;
  u16* dst = Vt + (size_t)bh * SEQ * HD;
#pragma unroll
  for (int i = 0; i < 2; i++) {
    int c = t + i * 256, s = c >> 3, cp = c & 7;
    *(uint4*)&ld[s * 72 + ((cp ^ (s >> 3)) << 3)] =
        *(const uint4*)(src + (size_t)s * HD + cp * 8);
  }
  __syncthreads();
#pragma unroll
  for (int i = 0; i < 2; i++) {
    int c = t + i * 256, d = c >> 3, sc = c & 7;   // sc = s5s4s3 of local key
    u16 os[8];
#pragma unroll
    for (int j = 0; j < 8; j++) {
      int s = sc * 8 + j;
      os[j] = ld[s * 72 + (((d >> 3) ^ (s >> 3)) << 3) + (d & 7)];
    }
    // c(s) = 32*s5 + 16*s3 + 8*s2 + 4*s4 + s1s0
    int cb = ((sc >> 2) << 5) + ((sc & 1) << 4) + (((sc >> 1) & 1) << 2);
    *(uint2*)(dst + (size_t)d * SEQ + s0 + cb)     = *(const uint2*)&os[0];
    *(uint2*)(dst + (size_t)d * SEQ + s0 + cb + 8) = *(const uint2*)&os[4];
  }
}

// ------------ flash attention, swapped-QK in-register softmax --------------
// 8 waves, 128-row q tile, K/V LDS double-buffered (1 barrier/tile),
// lane-local softmax (P feeds PV directly; key perm pre-baked into Vt),
// chunk-XOR LDS swizzle (R13: bank conflicts 8.42M -> 0).
// R14: __launch_bounds__(512, 4). LDS (49KB -> 2 blocks/CU -> 4 waves/SIMD)
// is the binding occupancy limit; without the hint the allocator targeted
// max occupancy and squeezed to 44 VGPRs, recomputing all loop-invariant
// LDS addresses each tile (~4x intrinsic VALU). 4 waves/EU => 128-VGPR
// budget: hoist addresses, schedule deeper.
__global__ __launch_bounds__(512, 4) void attn_flash_k(const u16* __restrict__ Qg,
    const u16* __restrict__ Kg, const u16* __restrict__ Vtg, u16* __restrict__ Og) {
  __shared__ __align__(16) u16 q_s[128 * 64];     // Q staging (XOR-swizzled)
  __shared__ __align__(16) u16 k_s[2][64 * 64];   // K rows, double-buffered
  __shared__ __align__(16) u16 vt_s[2][64 * 64];  // V^T rows (key-permuted)
  int t = threadIdx.x, lane = t & 63, w = t >> 6;   // w in 0..7
  int l15 = lane & 15, quad = lane >> 4;
  int lid = blockIdx.x;                      // 512 blocks
  int nid = (lid & 7) * 64 + (lid >> 3);     // XCD-contiguous remap
  int bh = nid >> 4;                         // 16 q-tiles per (b,h)
  int qt0 = (nid & 15) * 128;
  int b = bh >> 3, h = bh & 7;
  const u16* Qp = Qg + (size_t)bh * SEQ * HD;
  const u16* Kp = Kg + (size_t)bh * SEQ * HD;
  const u16* Vp = Vtg + (size_t)bh * SEQ * HD;   // [d][s'] permuted
  int row = t >> 3, ch = t & 7;    // staging: K -> row=key, V^T -> row=d
  int schu = (ch ^ (row & 7)) << 3;            // swizzled staging slot
  int r7 = l15 & 7;                            // read-side row bits

  // stage Q tile (128 rows, swizzled)
#pragma unroll
  for (int i = 0; i < 2; i++) {
    int c = t + i * 512, qr = c >> 3, qc = c & 7;
    *(uint4*)&q_s[qr * 64 + ((qc ^ (qr & 7)) << 3)] =
        *(const uint4*)(Qp + (size_t)(qt0 + qr) * HD + qc * 8);
  }
  // stage K/V tile 0 into buf0, issue tile 1 loads
  uint4 kr = *(const uint4*)(Kp + (size_t)row * HD + ch * 8);
  uint4 vr = *(const uint4*)(Vp + (size_t)row * SEQ + ch * 8);
  *(uint4*)&k_s[0][row * 64 + schu] = kr;
  *(uint4*)&vt_s[0][row * 64 + schu] = vr;
  kr = *(const uint4*)(Kp + (size_t)(64 + row) * HD + ch * 8);
  vr = *(const uint4*)(Vp + (size_t)row * SEQ + 64 + ch * 8);
  __syncthreads();                 // Q + tile0 visible
  bf16x8 qa[2];
  qa[0] = *(const bf16x8*)&q_s[(w * 16 + l15) * 64 + ((quad ^ r7) << 3)];
  qa[1] = *(const bf16x8*)&q_s[(w * 16 + l15) * 64 + (((4 + quad) ^ r7) << 3)];
  f32x4 z4 = {0.f, 0.f, 0.f, 0.f};
  f32x4 of[4];                     // of[nd][r] = O^T[d=nd*16+quad*4+r][q]
#pragma unroll
  for (int n = 0; n < 4; n++) of[n] = z4;
  float lrun = 0.f;                // one query per lane -> scalar sum

  for (int kt = 0; kt < SEQ; kt += 64) {
    int cur = (kt >> 6) & 1;
    // S^T = mfma(K, Q): sf[n][r] = S[q=w*16+l15][key=n*16+quad*4+r]
    f32x4 sf[4];
#pragma unroll
    for (int n = 0; n < 4; n++) sf[n] = z4;
    __builtin_amdgcn_s_setprio(1);
#pragma unroll
    for (int kk = 0; kk < 2; kk++)
#pragma unroll
      for (int n = 0; n < 4; n++) {
        bf16x8 kb = *(const bf16x8*)&k_s[cur][(n * 16 + l15) * 64 +
                                             (((kk * 4 + quad) ^ r7) << 3)];
        sf[n] = __builtin_amdgcn_mfma_f32_16x16x32_bf16(kb, qa[kk], sf[n], 0, 0, 0);
      }
    __builtin_amdgcn_s_setprio(0);
    // lane-local softmax: exp2 (Q carried log2e/8), pack bf16 pairs in-reg
    u32 p32[4][2];
#pragma unroll
    for (int n = 0; n < 4; n++) {
      float e0 = exp2f(sf[n][0]), e1 = exp2f(sf[n][1]);
      float e2 = exp2f(sf[n][2]), e3 = exp2f(sf[n][3]);
      lrun += (e0 + e1) + (e2 + e3);
      asm("v_cvt_pk_bf16_f32 %0, %1, %2" : "=v"(p32[n][0]) : "v"(e0), "v"(e1));
      asm("v_cvt_pk_bf16_f32 %0, %1, %2" : "=v"(p32[n][1]) : "v"(e2), "v"(e3));
    }
    // O^T += V^T P^T: pbv is lane-local (key order pre-baked into Vt)
    __builtin_amdgcn_s_setprio(1);
#pragma unroll
    for (int kk = 0; kk < 2; kk++) {
      u32 pb[4] = {p32[kk * 2][0], p32[kk * 2][1], p32[kk * 2 + 1][0], p32[kk * 2 + 1][1]};
      bf16x8 pbv;
      __builtin_memcpy(&pbv, pb, 16);
#pragma unroll
      for (int nd = 0; nd < 4; nd++) {
        bf16x8 va = *(const bf16x8*)&vt_s[cur][(nd * 16 + l15) * 64 +
                                              (((kk * 4 + quad) ^ r7) << 3)];
        of[nd] = __builtin_amdgcn_mfma_f32_16x16x32_bf16(va, pbv, of[nd], 0, 0, 0);
      }
    }
    __builtin_amdgcn_s_setprio(0);
    // stage next tile into buf[cur^1]; issue tile kt+128 loads
    if (kt + 64 < SEQ) {
      *(uint4*)&k_s[cur ^ 1][row * 64 + schu] = kr;
      *(uint4*)&vt_s[cur ^ 1][row * 64 + schu] = vr;
      if (kt + 128 < SEQ) {
        kr = *(const uint4*)(Kp + (size_t)(kt + 128 + row) * HD + ch * 8);
        vr = *(const uint4*)(Vp + (size_t)row * SEQ + kt + 128 + ch * 8);
      }
    }
    __syncthreads();               // single barrier per tile
  }
  // norm: lane's partial covers its quad's keys; sum across quads (xor 16,32)
  float l = lrun;
  l += __shfl_xor(l, 16);
  l += __shfl_xor(l, 32);
  float inv = 1.f / l;
  size_t orow = (size_t)(b * SEQ + qt0 + w * 16 + l15);
#pragma unroll
  for (int nd = 0; nd < 4; nd++) {
    uint2 uv;
    uv.x = (u32)f2b(of[nd][0] * inv) | ((u32)f2b(of[nd][1] * inv) << 16);
    uv.y = (u32)f2b(of[nd][2] * inv) | ((u32)f2b(of[nd][3] * inv) << 16);
    *(uint2*)&Og[orow * DIMM + h * HD + nd * 16 + quad * 4] = uv;
  }
}

// ---------------------------------------------------------------------------
extern "C" void kernel_launch(void* const* d_in, const int* in_sizes, int n_in,
                              void* d_out, int out_size, void* d_ws, size_t ws_size,
                              hipStream_t stream) {
  const float* x    = (const float*)d_in[0];
  const float* rc   = (const float*)d_in[1];
  const float* rsn  = (const float*)d_in[2];
  const float* n1g  = (const float*)d_in[3];
  const float* n1b  = (const float*)d_in[4];
  const float* n2g  = (const float*)d_in[5];
  const float* n2b  = (const float*)d_in[6];
  const float* wqkv = (const float*)d_in[7];
  const float* bqkv = (const float*)d_in[8];
  const float* wprj = (const float*)d_in[9];
  const float* bprj = (const float*)d_in[10];
  const float* wf1  = (const float*)d_in[11];
  const float* bf1  = (const float*)d_in[12];
  const float* wf2  = (const float*)d_in[13];
  const float* bf2  = (const float*)d_in[14];

  char* p = (char*)d_ws;
  u16*   wqkvT = (u16*)p;                   // 1.5 MB
  u16*   wprjT = (u16*)(p + (2u  << 20));   // 0.5 MB
  u16*   wf1T  = (u16*)(p + (3u  << 20));   // 2 MB
  u16*   wf2T  = (u16*)(p + (5u  << 20));   // 2 MB
  u16*   h1    = (u16*)(p + (8u  << 20));   // 8 MB bf16: LN1 out / ob / h2
  u16*   qkvb  = (u16*)(p + (16u << 20));   // 24 MB bf16
  u16*   Vt    = (u16*)(p + (40u << 20));   // 8 MB bf16 (dead before FC1's mid)
  u16*   Qb    = (u16*)(p + (64u << 20));   // 8 MB bf16
  u16*   Kb    = (u16*)(p + (72u << 20));   // 8 MB bf16
  u16*   Vb    = (u16*)(p + (80u << 20));   // 8 MB bf16
  float* x2    = (float*)(p + (88u << 20)); // 16 MB f32 residual stream
  u16*   ob    = h1;                        // h1 dead after QKV gemm
  u16*   h2    = h1;                        // ob dead after proj gemm
  u16*   mid   = qkvb;                      // 32 MB bf16 region (qkvb+Vt dead)

  transpose_all_k<<<dim3((SZ_QKV + SZ_PRJ + SZ_F1 + SZ_F2) / 256), 256, 0, stream>>>(
      wqkv, wprj, wf1, wf2, wqkvT, wprjT, wf1T, wf2T);

  ln_f32b_k<<<dim3(BS / 4), 256, 0, stream>>>(x, n1g, n1b, h1);

  gemm_bt<3, 64, 128, 32><<<dim3(NQKV / 128, BS / 64), 256, 0, stream>>>(h1, wqkvT, bqkv, qkvb, nullptr, NQKV, DIMM);

  rope_k<<<dim3(BS * NQKV / 8 / 256), 256, 0, stream>>>(qkvb, rc, rsn, Qb, Kb, Vb);

  vtrans_k<<<dim3(32 * (SEQ / 64)), 256, 0, stream>>>(Vb, Vt);

  attn_flash_k<<<dim3(32 * (SEQ / 128)), 512, 0, stream>>>(Qb, Kb, Vt, ob);

  gemm_bt<1, 64, 64, 64><<<dim3(DIMM / 64, BS / 64), 256, 0, stream>>>(ob, wprjT, bprj, x2, x, DIMM, DIMM);

  ln_f32b_k<<<dim3(BS / 4), 256, 0, stream>>>(x2, n2g, n2b, h2);

  gemm_bt<2, 64, 128, 32><<<dim3(DFF / 128, BS / 64), 256, 0, stream>>>(h2, wf1T, bf1, mid, nullptr, DFF, DIMM);

  gemm_bt<1, 64, 64, 64><<<dim3(DIMM / 64, BS / 64), 256, 0, stream>>>(mid, wf2T, bf2, (float*)d_out, x2, DIMM, DFF);
}

// Round 16
// 281.711 us; speedup vs baseline: 1.0180x; 1.0138x over previous
//
#include <hip/hip_runtime.h>
#include <cstdint>
#include <cstddef>

typedef unsigned short u16;
typedef unsigned int   u32;
typedef __bf16 bf16x8 __attribute__((ext_vector_type(8)));
typedef float  f32x4  __attribute__((ext_vector_type(4)));

#define BS   8192
#define DIMM 512
#define NH   8
#define HD   64
#define SEQ  2048
#define DFF  2048
#define NQKV 1536

// async global->LDS, 16B/lane; LDS dest = wave-uniform base + lane*16
#define GLD16(g, l) __builtin_amdgcn_global_load_lds( \
    (__attribute__((address_space(1))) const void*)(g), \
    (__attribute__((address_space(3))) void*)(l), 16, 0, 0)

__device__ __forceinline__ float b2f(u16 s) {
  u32 u = ((u32)s) << 16;
  float f; __builtin_memcpy(&f, &u, 4); return f;
}
__device__ __forceinline__ u16 f2b(float f) {
  u32 u; __builtin_memcpy(&u, &f, 4);
  u += 0x7fffu + ((u >> 16) & 1u);   // RNE
  return (u16)(u >> 16);
}

// ---- merged weight transpose+convert: 4 weights, one launch ---------------
#define SZ_QKV (DIMM * NQKV)
#define SZ_PRJ (DIMM * DIMM)
#define SZ_F1  (DIMM * DFF)
#define SZ_F2  (DFF * DIMM)
__global__ __launch_bounds__(256) void transpose_all_k(
    const float* __restrict__ w_qkv, const float* __restrict__ w_prj,
    const float* __restrict__ w_f1,  const float* __restrict__ w_f2,
    u16* __restrict__ o_qkv, u16* __restrict__ o_prj,
    u16* __restrict__ o_f1,  u16* __restrict__ o_f2) {
  int idx = blockIdx.x * 256 + threadIdx.x;
  const float* W; u16* O; int Kd, Nd, off;
  if (idx < SZ_QKV)                         { W = w_qkv; O = o_qkv; Kd = DIMM; Nd = NQKV; off = idx; }
  else if (idx < SZ_QKV + SZ_PRJ)           { W = w_prj; O = o_prj; Kd = DIMM; Nd = DIMM; off = idx - SZ_QKV; }
  else if (idx < SZ_QKV + SZ_PRJ + SZ_F1)   { W = w_f1;  O = o_f1;  Kd = DIMM; Nd = DFF;  off = idx - SZ_QKV - SZ_PRJ; }
  else                                      { W = w_f2;  O = o_f2;  Kd = DFF;  Nd = DIMM; off = idx - SZ_QKV - SZ_PRJ - SZ_F1; }
  int n = off / Kd, k = off - n * Kd;
  O[off] = f2b(W[(size_t)k * Nd + n]);
}

// ---------------- LayerNorm f32 -> bf16 (one wave per 512-row) -------------
__global__ __launch_bounds__(256) void ln_f32b_k(const float* __restrict__ X,
    const float* __restrict__ G, const float* __restrict__ Bb, u16* __restrict__ out) {
  int w = threadIdx.x >> 6, lane = threadIdx.x & 63;
  size_t row = (size_t)blockIdx.x * 4 + w;
  const float* xr = X + row * DIMM;
  float v[8];
  *(float4*)&v[0] = *(const float4*)(xr + lane * 8);
  *(float4*)&v[4] = *(const float4*)(xr + lane * 8 + 4);
  float s = 0.f, s2 = 0.f;
#pragma unroll
  for (int j = 0; j < 8; j++) { s += v[j]; s2 += v[j] * v[j]; }
#pragma unroll
  for (int m = 1; m < 64; m <<= 1) { s += __shfl_xor(s, m); s2 += __shfl_xor(s2, m); }
  float mu = s * (1.f / DIMM);
  float rsd = rsqrtf(s2 * (1.f / DIMM) - mu * mu + 1e-5f);
  float g[8], bb[8];
  *(float4*)&g[0]  = *(const float4*)(G + lane * 8);
  *(float4*)&g[4]  = *(const float4*)(G + lane * 8 + 4);
  *(float4*)&bb[0] = *(const float4*)(Bb + lane * 8);
  *(float4*)&bb[4] = *(const float4*)(Bb + lane * 8 + 4);
  uint4 ov; u16* os = (u16*)&ov;
#pragma unroll
  for (int j = 0; j < 8; j++) os[j] = f2b((v[j] - mu) * rsd * g[j] + bb[j]);
  *(uint4*)(out + row * DIMM + lane * 8) = ov;
}

// -------- MFMA GEMM: C[M,N] = A[M,K](bf16) @ BT[N,K](bf16)^T + bias --------
// 2-phase double-buffered pipeline (verified best: R9/R11 bench; T4
// counted-vmcnt REGRESSED ~35us; RoPE-fused epilogue REGRESSED ~15us).
// LDS tiles XOR-swizzled (T2) via pre-swizzled GLOBAL source; read side
// applies the same involution. Measured 0 bank conflicts (R6 counters).
// Macros (not lambdas): R2/R3 toolchain fail.
// EPI 0: f32   EPI 1: f32 (v + f32 resid)   EPI 2: gelu->bf16   EPI 3: bf16
template <int EPI, int TM, int TN, int BK>
__global__ __launch_bounds__(256) void gemm_bt(const u16* __restrict__ A,
    const u16* __restrict__ BT, const float* __restrict__ bias,
    void* __restrict__ Cout, const float* __restrict__ resid, int N, int Kd) {
  constexpr int CPR  = BK / 8;               // 16B chunks per row
  constexpr int CPRB = (BK == 64) ? 3 : 2;
  constexpr int RS   = (BK == 64) ? 0 : 1;   // swizzle: vary per 128B window
  constexpr int KK   = BK / 32;
  constexpr int WROWS = (TN == 128) ? TM / 2 : TM / 4;
  constexpr int MT   = WROWS / 16;
  __shared__ __align__(16) u16 a_s[2][TM * BK];
  __shared__ __align__(16) u16 b_s[2][TN * BK];
  int t = threadIdx.x, lane = t & 63, w = t >> 6;
  int l15 = lane & 15, quad = lane >> 4;
  int gx = gridDim.x;
  int lid = blockIdx.x + gx * blockIdx.y;
  int per = (gx * gridDim.y) >> 3;
  int nid = (lid & 7) * per + (lid >> 3);    // XCD-contiguous remap
  int bx = nid % gx, by = nid / gx;
  int m0 = by * TM, n0 = bx * TN;
  int wm = (TN == 128) ? (w >> 1) * WROWS : w * WROWS;
  int wn = (TN == 128) ? (w & 1) * 64 : 0;
  f32x4 z4 = {0.f, 0.f, 0.f, 0.f};
  f32x4 acc[MT][4];
#pragma unroll
  for (int i = 0; i < MT; i++)
#pragma unroll
    for (int j = 0; j < 4; j++) acc[i][j] = z4;

#define GSTAGE(buf, ts) do {                                                  \
    int k0_ = (ts) * BK;                                                      \
    _Pragma("unroll")                                                         \
    for (int i = 0; i < TM * CPR / 256; i++) {                                \
      int c_ = t + i * 256;                                                   \
      int row_ = c_ >> CPRB, pos_ = c_ & (CPR - 1);                           \
      int ch_ = (pos_ ^ (row_ >> RS)) & (CPR - 1);                            \
      GLD16(A + (size_t)(m0 + row_) * Kd + k0_ + ch_ * 8, &a_s[buf][c_ * 8]); \
    }                                                                         \
    _Pragma("unroll")                                                         \
    for (int i = 0; i < TN * CPR / 256; i++) {                                \
      int c_ = t + i * 256;                                                   \
      int row_ = c_ >> CPRB, pos_ = c_ & (CPR - 1);                           \
      int ch_ = (pos_ ^ (row_ >> RS)) & (CPR - 1);                            \
      GLD16(BT + (size_t)(n0 + row_) * Kd + k0_ + ch_ * 8, &b_s[buf][c_ * 8]);\
    }                                                                         \
  } while (0)

#define GCOMPUTE(buf) do {                                                    \
    bf16x8 af[MT][KK], bfm[4][KK];                                            \
    _Pragma("unroll")                                                         \
    for (int mt = 0; mt < MT; mt++) {                                         \
      _Pragma("unroll")                                                       \
      for (int kk = 0; kk < KK; kk++) {                                       \
        int row_ = wm + mt * 16 + l15;                                        \
        int pos_ = ((kk * 4 + quad) ^ (row_ >> RS)) & (CPR - 1);              \
        af[mt][kk] = *(const bf16x8*)&a_s[buf][row_ * BK + pos_ * 8];         \
      }                                                                       \
    }                                                                         \
    _Pragma("unroll")                                                         \
    for (int nt = 0; nt < 4; nt++) {                                          \
      _Pragma("unroll")                                                       \
      for (int kk = 0; kk < KK; kk++) {                                       \
        int row_ = wn + nt * 16 + l15;                                        \
        int pos_ = ((kk * 4 + quad) ^ (row_ >> RS)) & (CPR - 1);              \
        bfm[nt][kk] = *(const bf16x8*)&b_s[buf][row_ * BK + pos_ * 8];        \
      }                                                                       \
    }                                                                         \
    _Pragma("unroll")                                                         \
    for (int kk = 0; kk < KK; kk++)                                           \
      _Pragma("unroll")                                                       \
      for (int mt = 0; mt < MT; mt++)                                         \
        _Pragma("unroll")                                                     \
        for (int nt = 0; nt < 4; nt++)                                        \
          acc[mt][nt] = __builtin_amdgcn_mfma_f32_16x16x32_bf16(              \
              af[mt][kk], bfm[nt][kk], acc[mt][nt], 0, 0, 0);                 \
  } while (0)

  GSTAGE(0, 0);
  __syncthreads();                 // tile 0 ready (full latency exposed once)
  int nsteps = Kd / BK;            // always even (8/16/32)
  for (int ts = 0; ts < nsteps; ts += 2) {
    GSTAGE(1, ts + 1);             // issue next tile's loads first
    GCOMPUTE(0);
    __syncthreads();               // implicit vmcnt(0) AFTER compute
    if (ts + 2 < nsteps) GSTAGE(0, ts + 2);
    GCOMPUTE(1);
    __syncthreads();
  }
#undef GSTAGE
#undef GCOMPUTE

#pragma unroll
  for (int nt = 0; nt < 4; nt++) {
    int col = n0 + wn + nt * 16 + l15;
    float bv = bias[col];
#pragma unroll
    for (int mt = 0; mt < MT; mt++) {
#pragma unroll
      for (int r = 0; r < 4; r++) {
        int rw = m0 + wm + mt * 16 + quad * 4 + r;
        float v = acc[mt][nt][r] + bv;
        size_t off = (size_t)rw * N + col;
        if (EPI == 0) {
          ((float*)Cout)[off] = v;
        } else if (EPI == 1) {
          ((float*)Cout)[off] = v + resid[off];
        } else if (EPI == 2) {
          ((u16*)Cout)[off] = f2b(0.5f * v * (1.f + erff(v * 0.70710678118654752f)));
        } else {
          ((u16*)Cout)[off] = f2b(v);
        }
      }
    }
  }
}

// ------- RoPE + reorg qkv[BS][1536] bf16 -> Q,K,V [B*H][S][HD] bf16 --------
// Q pre-scaled by (1/sqrt(HD)) * log2(e) so attention can use exp2.
#define QSCALE 0.18033688f
__global__ __launch_bounds__(256) void rope_k(const u16* __restrict__ qkv,
    const float* __restrict__ C, const float* __restrict__ Sn,
    u16* __restrict__ Qo, u16* __restrict__ Ko, u16* __restrict__ Vo) {
  int idx = blockIdx.x * 256 + threadIdx.x;   // one 8-elem chunk
  int row = idx / 192;                        // (b*SEQ + s)
  int cn = idx - row * 192;
  int n0 = cn * 8;
  int comp = n0 >> 9;
  int hh = (n0 >> 6) & 7;
  int d0 = n0 & 63;
  int b = row >> 11, s = row & 2047;
  const u16* src = qkv + (size_t)row * NQKV;
  uint4 val = *(const uint4*)(src + n0);
  u16* vs = (u16*)&val;
  size_t oo = ((size_t)((b << 3) + hh) * SEQ + s) * HD + d0;
  if (comp == 2) { *(uint4*)(Vo + oo) = val; return; }
  uint4 pv = *(const uint4*)(src + (n0 ^ 32));        // rotate-half partner
  u16* ps = (u16*)&pv;
  float cv[8], sv[8];
  *(float4*)&cv[0] = *(const float4*)(C + s * HD + d0);
  *(float4*)&cv[4] = *(const float4*)(C + s * HD + d0 + 4);
  *(float4*)&sv[0] = *(const float4*)(Sn + s * HD + d0);
  *(float4*)&sv[4] = *(const float4*)(Sn + s * HD + d0 + 4);
  float sgn = (d0 & 32) ? 1.f : -1.f;
  float sc = (comp == 0) ? QSCALE : 1.f;
  uint4 ov; u16* os = (u16*)&ov;
#pragma unroll
  for (int j = 0; j < 8; j++)
    os[j] = f2b(sc * (b2f(vs[j]) * cv[j] + sgn * b2f(ps[j]) * sv[j]));
  *(uint4*)((comp == 0 ? Qo : Ko) + oo) = ov;
}

// ------------- V transpose: [bh][s][d] -> Vt [bh][d][s'] (bf16) ------------
// Key order PERMUTED within each 64-key block so attn's PV B-operand maps
// lane-local P registers with ZERO cross-lane exchange:
//   store key s (bits s5..s0) at c = {s5, s3, s2, s4, s1, s0}.
__global__ __launch_bounds__(256) void vtrans_k(const u16* __restrict__ V,
                                                u16* __restrict__ Vt) {
  __shared__ u16 ld[64 * 72];
  int t = threadIdx.x;
  int bh = blockIdx.x >> 5;          // 32 s-tiles per bh
  int s0 = (blockIdx.x & 31) * 64;
  const u16* src = V + (size_t)bh * SEQ * HD + (size_t)s0 * HD;
  u16* dst = Vt + (size_t)bh * SEQ * HD;
#pragma unroll
  for (int i = 0; i < 2; i++) {
    int c = t + i * 256, s = c >> 3, cp = c & 7;
    *(uint4*)&ld[s * 72 + ((cp ^ (s >> 3)) << 3)] =
        *(const uint4*)(src + (size_t)s * HD + cp * 8);
  }
  __syncthreads();
#pragma unroll
  for (int i = 0; i < 2; i++) {
    int c = t + i * 256, d = c >> 3, sc = c & 7;   // sc = s5s4s3 of local key
    u16 os[8];
#pragma unroll
    for (int j = 0; j < 8; j++) {
      int s = sc * 8 + j;
      os[j] = ld[s * 72 + (((d >> 3) ^ (s >> 3)) << 3) + (d & 7)];
    }
    // c(s) = 32*s5 + 16*s3 + 8*s2 + 4*s4 + s1s0
    int cb = ((sc >> 2) << 5) + ((sc & 1) << 4) + (((sc >> 1) & 1) << 2);
    *(uint2*)(dst + (size_t)d * SEQ + s0 + cb)     = *(const uint2*)&os[0];
    *(uint2*)(dst + (size_t)d * SEQ + s0 + cb + 8) = *(const uint2*)&os[4];
  }
}

// ------------ flash attention, swapped-QK in-register softmax --------------
// 8 waves, 128-row q tile, K/V LDS double-buffered (1 barrier/tile),
// lane-local softmax (P feeds PV directly; key perm pre-baked into Vt),
// chunk-XOR LDS swizzle (R13: bank conflicts 8.42M -> 0).
// R15: exp2f -> __builtin_amdgcn_exp2f (raw v_exp_f32; libcall expansion
// was ~5 VALU insts each x16/tile = the largest slice of the 650-cyc
// per-wave-tile VALU load). Arguments are bounded softmax scores (Q carries
// log2e/8) -- raw instruction semantics sufficient. P pack words laid out
// flat (p32[8]): pbv(kk) = p32[4kk..4kk+3] verified == PV key order, kills
// the per-tile register-gather movs.
__global__ __launch_bounds__(512, 4) void attn_flash_k(const u16* __restrict__ Qg,
    const u16* __restrict__ Kg, const u16* __restrict__ Vtg, u16* __restrict__ Og) {
  __shared__ __align__(16) u16 q_s[128 * 64];     // Q staging (XOR-swizzled)
  __shared__ __align__(16) u16 k_s[2][64 * 64];   // K rows, double-buffered
  __shared__ __align__(16) u16 vt_s[2][64 * 64];  // V^T rows (key-permuted)
  int t = threadIdx.x, lane = t & 63, w = t >> 6;   // w in 0..7
  int l15 = lane & 15, quad = lane >> 4;
  int lid = blockIdx.x;                      // 512 blocks
  int nid = (lid & 7) * 64 + (lid >> 3);     // XCD-contiguous remap
  int bh = nid >> 4;                         // 16 q-tiles per (b,h)
  int qt0 = (nid & 15) * 128;
  int b = bh >> 3, h = bh & 7;
  const u16* Qp = Qg + (size_t)bh * SEQ * HD;
  const u16* Kp = Kg + (size_t)bh * SEQ * HD;
  const u16* Vp = Vtg + (size_t)bh * SEQ * HD;   // [d][s'] permuted
  int row = t >> 3, ch = t & 7;    // staging: K -> row=key, V^T -> row=d
  int schu = (ch ^ (row & 7)) << 3;            // swizzled staging slot
  int r7 = l15 & 7;                            // read-side row bits

  // stage Q tile (128 rows, swizzled)
#pragma unroll
  for (int i = 0; i < 2; i++) {
    int c = t + i * 512, qr = c >> 3, qc = c & 7;
    *(uint4*)&q_s[qr * 64 + ((qc ^ (qr & 7)) << 3)] =
        *(const uint4*)(Qp + (size_t)(qt0 + qr) * HD + qc * 8);
  }
  // stage K/V tile 0 into buf0, issue tile 1 loads
  uint4 kr = *(const uint4*)(Kp + (size_t)row * HD + ch * 8);
  uint4 vr = *(const uint4*)(Vp + (size_t)row * SEQ + ch * 8);
  *(uint4*)&k_s[0][row * 64 + schu] = kr;
  *(uint4*)&vt_s[0][row * 64 + schu] = vr;
  kr = *(const uint4*)(Kp + (size_t)(64 + row) * HD + ch * 8);
  vr = *(const uint4*)(Vp + (size_t)row * SEQ + 64 + ch * 8);
  __syncthreads();                 // Q + tile0 visible
  bf16x8 qa[2];
  qa[0] = *(const bf16x8*)&q_s[(w * 16 + l15) * 64 + ((quad ^ r7) << 3)];
  qa[1] = *(const bf16x8*)&q_s[(w * 16 + l15) * 64 + (((4 + quad) ^ r7) << 3)];
  f32x4 z4 = {0.f, 0.f, 0.f, 0.f};
  f32x4 of[4];                     // of[nd][r] = O^T[d=nd*16+quad*4+r][q]
#pragma unroll
  for (int n = 0; n < 4; n++) of[n] = z4;
  float lrun = 0.f;                // one query per lane -> scalar sum

  for (int kt = 0; kt < SEQ; kt += 64) {
    int cur = (kt >> 6) & 1;
    // S^T = mfma(K, Q): sf[n][r] = S[q=w*16+l15][key=n*16+quad*4+r]
    f32x4 sf[4];
#pragma unroll
    for (int n = 0; n < 4; n++) sf[n] = z4;
    __builtin_amdgcn_s_setprio(1);
#pragma unroll
    for (int kk = 0; kk < 2; kk++)
#pragma unroll
      for (int n = 0; n < 4; n++) {
        bf16x8 kb = *(const bf16x8*)&k_s[cur][(n * 16 + l15) * 64 +
                                             (((kk * 4 + quad) ^ r7) << 3)];
        sf[n] = __builtin_amdgcn_mfma_f32_16x16x32_bf16(kb, qa[kk], sf[n], 0, 0, 0);
      }
    __builtin_amdgcn_s_setprio(0);
    // lane-local softmax: raw v_exp_f32 (Q carried log2e/8), pack bf16 pairs
    u32 p32[8];                    // pbv(kk) = p32[4kk..4kk+3]
#pragma unroll
    for (int n = 0; n < 4; n++) {
      float e0 = __builtin_amdgcn_exp2f(sf[n][0]);
      float e1 = __builtin_amdgcn_exp2f(sf[n][1]);
      float e2 = __builtin_amdgcn_exp2f(sf[n][2]);
      float e3 = __builtin_amdgcn_exp2f(sf[n][3]);
      lrun += (e0 + e1) + (e2 + e3);
      asm("v_cvt_pk_bf16_f32 %0, %1, %2" : "=v"(p32[n * 2])     : "v"(e0), "v"(e1));
      asm("v_cvt_pk_bf16_f32 %0, %1, %2" : "=v"(p32[n * 2 + 1]) : "v"(e2), "v"(e3));
    }
    // O^T += V^T P^T: pbv is lane-local (key order pre-baked into Vt)
    __builtin_amdgcn_s_setprio(1);
#pragma unroll
    for (int kk = 0; kk < 2; kk++) {
      bf16x8 pbv;
      __builtin_memcpy(&pbv, &p32[kk * 4], 16);
#pragma unroll
      for (int nd = 0; nd < 4; nd++) {
        bf16x8 va = *(const bf16x8*)&vt_s[cur][(nd * 16 + l15) * 64 +
                                              (((kk * 4 + quad) ^ r7) << 3)];
        of[nd] = __builtin_amdgcn_mfma_f32_16x16x32_bf16(va, pbv, of[nd], 0, 0, 0);
      }
    }
    __builtin_amdgcn_s_setprio(0);
    // stage next tile into buf[cur^1]; issue tile kt+128 loads
    if (kt + 64 < SEQ) {
      *(uint4*)&k_s[cur ^ 1][row * 64 + schu] = kr;
      *(uint4*)&vt_s[cur ^ 1][row * 64 + schu] = vr;
      if (kt + 128 < SEQ) {
        kr = *(const uint4*)(Kp + (size_t)(kt + 128 + row) * HD + ch * 8);
        vr = *(const uint4*)(Vp + (size_t)row * SEQ + kt + 128 + ch * 8);
      }
    }
    __syncthreads();               // single barrier per tile
  }
  // norm: lane's partial covers its quad's keys; sum across quads (xor 16,32)
  float l = lrun;
  l += __shfl_xor(l, 16);
  l += __shfl_xor(l, 32);
  float inv = 1.f / l;
  size_t orow = (size_t)(b * SEQ + qt0 + w * 16 + l15);
#pragma unroll
  for (int nd = 0; nd < 4; nd++) {
    uint2 uv;
    uv.x = (u32)f2b(of[nd][0] * inv) | ((u32)f2b(of[nd][1] * inv) << 16);
    uv.y = (u32)f2b(of[nd][2] * inv) | ((u32)f2b(of[nd][3] * inv) << 16);
    *(uint2*)&Og[orow * DIMM + h * HD + nd * 16 + quad * 4] = uv;
  }
}

// ---------------------------------------------------------------------------
extern "C" void kernel_launch(void* const* d_in, const int* in_sizes, int n_in,
                              void* d_out, int out_size, void* d_ws, size_t ws_size,
                              hipStream_t stream) {
  const float* x    = (const float*)d_in[0];
  const float* rc   = (const float*)d_in[1];
  const float* rsn  = (const float*)d_in[2];
  const float* n1g  = (const float*)d_in[3];
  const float* n1b  = (const float*)d_in[4];
  const float* n2g  = (const float*)d_in[5];
  const float* n2b  = (const float*)d_in[6];
  const float* wqkv = (const float*)d_in[7];
  const float* bqkv = (const float*)d_in[8];
  const float* wprj = (const float*)d_in[9];
  const float* bprj = (const float*)d_in[10];
  const float* wf1  = (const float*)d_in[11];
  const float* bf1  = (const float*)d_in[12];
  const float* wf2  = (const float*)d_in[13];
  const float* bf2  = (const float*)d_in[14];

  char* p = (char*)d_ws;
  u16*   wqkvT = (u16*)p;                   // 1.5 MB
  u16*   wprjT = (u16*)(p + (2u  << 20));   // 0.5 MB
  u16*   wf1T  = (u16*)(p + (3u  << 20));   // 2 MB
  u16*   wf2T  = (u16*)(p + (5u  << 20));   // 2 MB
  u16*   h1    = (u16*)(p + (8u  << 20));   // 8 MB bf16: LN1 out / ob / h2
  u16*   qkvb  = (u16*)(p + (16u << 20));   // 24 MB bf16
  u16*   Vt    = (u16*)(p + (40u << 20));   // 8 MB bf16 (dead before FC1's mid)
  u16*   Qb    = (u16*)(p + (64u << 20));   // 8 MB bf16
  u16*   Kb    = (u16*)(p + (72u << 20));   // 8 MB bf16
  u16*   Vb    = (u16*)(p + (80u << 20));   // 8 MB bf16
  float* x2    = (float*)(p + (88u << 20)); // 16 MB f32 residual stream
  u16*   ob    = h1;                        // h1 dead after QKV gemm
  u16*   h2    = h1;                        // ob dead after proj gemm
  u16*   mid   = qkvb;                      // 32 MB bf16 region (qkvb+Vt dead)

  transpose_all_k<<<dim3((SZ_QKV + SZ_PRJ + SZ_F1 + SZ_F2) / 256), 256, 0, stream>>>(
      wqkv, wprj, wf1, wf2, wqkvT, wprjT, wf1T, wf2T);

  ln_f32b_k<<<dim3(BS / 4), 256, 0, stream>>>(x, n1g, n1b, h1);

  gemm_bt<3, 64, 128, 32><<<dim3(NQKV / 128, BS / 64), 256, 0, stream>>>(h1, wqkvT, bqkv, qkvb, nullptr, NQKV, DIMM);

  rope_k<<<dim3(BS * NQKV / 8 / 256), 256, 0, stream>>>(qkvb, rc, rsn, Qb, Kb, Vb);

  vtrans_k<<<dim3(32 * (SEQ / 64)), 256, 0, stream>>>(Vb, Vt);

  attn_flash_k<<<dim3(32 * (SEQ / 128)), 512, 0, stream>>>(Qb, Kb, Vt, ob);

  gemm_bt<1, 64, 64, 64><<<dim3(DIMM / 64, BS / 64), 256, 0, stream>>>(ob, wprjT, bprj, x2, x, DIMM, DIMM);

  ln_f32b_k<<<dim3(BS / 4), 256, 0, stream>>>(x2, n2g, n2b, h2);

  gemm_bt<2, 64, 128, 32><<<dim3(DFF / 128, BS / 64), 256, 0, stream>>>(h2, wf1T, bf1, mid, nullptr, DFF, DIMM);

  gemm_bt<1, 64, 64, 64><<<dim3(DIMM / 64, BS / 64), 256, 0, stream>>>(mid, wf2T, bf2, (float*)d_out, x2, DIMM, DFF);
}

// Round 18
// 280.269 us; speedup vs baseline: 1.0232x; 1.0051x over previous
//
#include <hip/hip_runtime.h>
#include <cstdint>
#include <cstddef>

typedef unsigned short u16;
typedef unsigned int   u32;
typedef __bf16 bf16x8 __attribute__((ext_vector_type(8)));
typedef float  f32x4  __attribute__((ext_vector_type(4)));

#define BS   8192
#define DIMM 512
#define NH   8
#define HD   64
#define SEQ  2048
#define DFF  2048
#define NQKV 1536

// async global->LDS, 16B/lane; LDS dest = wave-uniform base + lane*16
#define GLD16(g, l) __builtin_amdgcn_global_load_lds( \
    (__attribute__((address_space(1))) const void*)(g), \
    (__attribute__((address_space(3))) void*)(l), 16, 0, 0)

__device__ __forceinline__ float b2f(u16 s) {
  u32 u = ((u32)s) << 16;
  float f; __builtin_memcpy(&f, &u, 4); return f;
}
__device__ __forceinline__ u16 f2b(float f) {
  u32 u; __builtin_memcpy(&u, &f, 4);
  u += 0x7fffu + ((u >> 16) & 1u);   // RNE
  return (u16)(u >> 16);
}

// ---- merged weight transpose+convert: 4 weights, one launch ---------------
#define SZ_QKV (DIMM * NQKV)
#define SZ_PRJ (DIMM * DIMM)
#define SZ_F1  (DIMM * DFF)
#define SZ_F2  (DFF * DIMM)
__global__ __launch_bounds__(256) void transpose_all_k(
    const float* __restrict__ w_qkv, const float* __restrict__ w_prj,
    const float* __restrict__ w_f1,  const float* __restrict__ w_f2,
    u16* __restrict__ o_qkv, u16* __restrict__ o_prj,
    u16* __restrict__ o_f1,  u16* __restrict__ o_f2) {
  int idx = blockIdx.x * 256 + threadIdx.x;
  const float* W; u16* O; int Kd, Nd, off;
  if (idx < SZ_QKV)                         { W = w_qkv; O = o_qkv; Kd = DIMM; Nd = NQKV; off = idx; }
  else if (idx < SZ_QKV + SZ_PRJ)           { W = w_prj; O = o_prj; Kd = DIMM; Nd = DIMM; off = idx - SZ_QKV; }
  else if (idx < SZ_QKV + SZ_PRJ + SZ_F1)   { W = w_f1;  O = o_f1;  Kd = DIMM; Nd = DFF;  off = idx - SZ_QKV - SZ_PRJ; }
  else                                      { W = w_f2;  O = o_f2;  Kd = DFF;  Nd = DIMM; off = idx - SZ_QKV - SZ_PRJ - SZ_F1; }
  int n = off / Kd, k = off - n * Kd;
  O[off] = f2b(W[(size_t)k * Nd + n]);
}

// ---------------- LayerNorm f32 -> bf16 (one wave per 512-row) -------------
__global__ __launch_bounds__(256) void ln_f32b_k(const float* __restrict__ X,
    const float* __restrict__ G, const float* __restrict__ Bb, u16* __restrict__ out) {
  int w = threadIdx.x >> 6, lane = threadIdx.x & 63;
  size_t row = (size_t)blockIdx.x * 4 + w;
  const float* xr = X + row * DIMM;
  float v[8];
  *(float4*)&v[0] = *(const float4*)(xr + lane * 8);
  *(float4*)&v[4] = *(const float4*)(xr + lane * 8 + 4);
  float s = 0.f, s2 = 0.f;
#pragma unroll
  for (int j = 0; j < 8; j++) { s += v[j]; s2 += v[j] * v[j]; }
#pragma unroll
  for (int m = 1; m < 64; m <<= 1) { s += __shfl_xor(s, m); s2 += __shfl_xor(s2, m); }
  float mu = s * (1.f / DIMM);
  float rsd = rsqrtf(s2 * (1.f / DIMM) - mu * mu + 1e-5f);
  float g[8], bb[8];
  *(float4*)&g[0]  = *(const float4*)(G + lane * 8);
  *(float4*)&g[4]  = *(const float4*)(G + lane * 8 + 4);
  *(float4*)&bb[0] = *(const float4*)(Bb + lane * 8);
  *(float4*)&bb[4] = *(const float4*)(Bb + lane * 8 + 4);
  uint4 ov; u16* os = (u16*)&ov;
#pragma unroll
  for (int j = 0; j < 8; j++) os[j] = f2b((v[j] - mu) * rsd * g[j] + bb[j]);
  *(uint4*)(out + row * DIMM + lane * 8) = ov;
}

// -------- MFMA GEMM: C[M,N] = A[M,K](bf16) @ BT[N,K](bf16)^T + bias --------
// 2-phase double-buffered pipeline (verified best: R9/R11 bench; T4
// counted-vmcnt REGRESSED ~35us; RoPE-fused epilogue REGRESSED ~15us).
// LDS tiles XOR-swizzled (T2) via pre-swizzled GLOBAL source; read side
// applies the same involution. Measured 0 bank conflicts (R6 counters).
// Macros (not lambdas): R2/R3 toolchain fail.
// EPI 0: f32   EPI 1: f32 (v + f32 resid)   EPI 2: gelu->bf16   EPI 3: bf16
template <int EPI, int TM, int TN, int BK>
__global__ __launch_bounds__(256) void gemm_bt(const u16* __restrict__ A,
    const u16* __restrict__ BT, const float* __restrict__ bias,
    void* __restrict__ Cout, const float* __restrict__ resid, int N, int Kd) {
  constexpr int CPR  = BK / 8;               // 16B chunks per row
  constexpr int CPRB = (BK == 64) ? 3 : 2;
  constexpr int RS   = (BK == 64) ? 0 : 1;   // swizzle: vary per 128B window
  constexpr int KK   = BK / 32;
  constexpr int WROWS = (TN == 128) ? TM / 2 : TM / 4;
  constexpr int MT   = WROWS / 16;
  __shared__ __align__(16) u16 a_s[2][TM * BK];
  __shared__ __align__(16) u16 b_s[2][TN * BK];
  int t = threadIdx.x, lane = t & 63, w = t >> 6;
  int l15 = lane & 15, quad = lane >> 4;
  int gx = gridDim.x;
  int lid = blockIdx.x + gx * blockIdx.y;
  int per = (gx * gridDim.y) >> 3;
  int nid = (lid & 7) * per + (lid >> 3);    // XCD-contiguous remap
  int bx = nid % gx, by = nid / gx;
  int m0 = by * TM, n0 = bx * TN;
  int wm = (TN == 128) ? (w >> 1) * WROWS : w * WROWS;
  int wn = (TN == 128) ? (w & 1) * 64 : 0;
  f32x4 z4 = {0.f, 0.f, 0.f, 0.f};
  f32x4 acc[MT][4];
#pragma unroll
  for (int i = 0; i < MT; i++)
#pragma unroll
    for (int j = 0; j < 4; j++) acc[i][j] = z4;

#define GSTAGE(buf, ts) do {                                                  \
    int k0_ = (ts) * BK;                                                      \
    _Pragma("unroll")                                                         \
    for (int i = 0; i < TM * CPR / 256; i++) {                                \
      int c_ = t + i * 256;                                                   \
      int row_ = c_ >> CPRB, pos_ = c_ & (CPR - 1);                           \
      int ch_ = (pos_ ^ (row_ >> RS)) & (CPR - 1);                            \
      GLD16(A + (size_t)(m0 + row_) * Kd + k0_ + ch_ * 8, &a_s[buf][c_ * 8]); \
    }                                                                         \
    _Pragma("unroll")                                                         \
    for (int i = 0; i < TN * CPR / 256; i++) {                                \
      int c_ = t + i * 256;                                                   \
      int row_ = c_ >> CPRB, pos_ = c_ & (CPR - 1);                           \
      int ch_ = (pos_ ^ (row_ >> RS)) & (CPR - 1);                            \
      GLD16(BT + (size_t)(n0 + row_) * Kd + k0_ + ch_ * 8, &b_s[buf][c_ * 8]);\
    }                                                                         \
  } while (0)

#define GCOMPUTE(buf) do {                                                    \
    bf16x8 af[MT][KK], bfm[4][KK];                                            \
    _Pragma("unroll")                                                         \
    for (int mt = 0; mt < MT; mt++) {                                         \
      _Pragma("unroll")                                                       \
      for (int kk = 0; kk < KK; kk++) {                                       \
        int row_ = wm + mt * 16 + l15;                                        \
        int pos_ = ((kk * 4 + quad) ^ (row_ >> RS)) & (CPR - 1);              \
        af[mt][kk] = *(const bf16x8*)&a_s[buf][row_ * BK + pos_ * 8];         \
      }                                                                       \
    }                                                                         \
    _Pragma("unroll")                                                         \
    for (int nt = 0; nt < 4; nt++) {                                          \
      _Pragma("unroll")                                                       \
      for (int kk = 0; kk < KK; kk++) {                                       \
        int row_ = wn + nt * 16 + l15;                                        \
        int pos_ = ((kk * 4 + quad) ^ (row_ >> RS)) & (CPR - 1);              \
        bfm[nt][kk] = *(const bf16x8*)&b_s[buf][row_ * BK + pos_ * 8];        \
      }                                                                       \
    }                                                                         \
    _Pragma("unroll")                                                         \
    for (int kk = 0; kk < KK; kk++)                                           \
      _Pragma("unroll")                                                       \
      for (int mt = 0; mt < MT; mt++)                                         \
        _Pragma("unroll")                                                     \
        for (int nt = 0; nt < 4; nt++)                                        \
          acc[mt][nt] = __builtin_amdgcn_mfma_f32_16x16x32_bf16(              \
              af[mt][kk], bfm[nt][kk], acc[mt][nt], 0, 0, 0);                 \
  } while (0)

  GSTAGE(0, 0);
  __syncthreads();                 // tile 0 ready (full latency exposed once)
  int nsteps = Kd / BK;            // always even (8/16/32)
  for (int ts = 0; ts < nsteps; ts += 2) {
    GSTAGE(1, ts + 1);             // issue next tile's loads first
    GCOMPUTE(0);
    __syncthreads();               // implicit vmcnt(0) AFTER compute
    if (ts + 2 < nsteps) GSTAGE(0, ts + 2);
    GCOMPUTE(1);
    __syncthreads();
  }
#undef GSTAGE
#undef GCOMPUTE

#pragma unroll
  for (int nt = 0; nt < 4; nt++) {
    int col = n0 + wn + nt * 16 + l15;
    float bv = bias[col];
#pragma unroll
    for (int mt = 0; mt < MT; mt++) {
#pragma unroll
      for (int r = 0; r < 4; r++) {
        int rw = m0 + wm + mt * 16 + quad * 4 + r;
        float v = acc[mt][nt][r] + bv;
        size_t off = (size_t)rw * N + col;
        if (EPI == 0) {
          ((float*)Cout)[off] = v;
        } else if (EPI == 1) {
          ((float*)Cout)[off] = v + resid[off];
        } else if (EPI == 2) {
          ((u16*)Cout)[off] = f2b(0.5f * v * (1.f + erff(v * 0.70710678118654752f)));
        } else {
          ((u16*)Cout)[off] = f2b(v);
        }
      }
    }
  }
}

// ------- RoPE + reorg qkv[BS][1536] bf16 -> Q,K,V [B*H][S][HD] bf16 --------
// Q pre-scaled by (1/sqrt(HD)) * log2(e) so attention can use exp2.
#define QSCALE 0.18033688f
__global__ __launch_bounds__(256) void rope_k(const u16* __restrict__ qkv,
    const float* __restrict__ C, const float* __restrict__ Sn,
    u16* __restrict__ Qo, u16* __restrict__ Ko, u16* __restrict__ Vo) {
  int idx = blockIdx.x * 256 + threadIdx.x;   // one 8-elem chunk
  int row = idx / 192;                        // (b*SEQ + s)
  int cn = idx - row * 192;
  int n0 = cn * 8;
  int comp = n0 >> 9;
  int hh = (n0 >> 6) & 7;
  int d0 = n0 & 63;
  int b = row >> 11, s = row & 2047;
  const u16* src = qkv + (size_t)row * NQKV;
  uint4 val = *(const uint4*)(src + n0);
  u16* vs = (u16*)&val;
  size_t oo = ((size_t)((b << 3) + hh) * SEQ + s) * HD + d0;
  if (comp == 2) { *(uint4*)(Vo + oo) = val; return; }
  uint4 pv = *(const uint4*)(src + (n0 ^ 32));        // rotate-half partner
  u16* ps = (u16*)&pv;
  float cv[8], sv[8];
  *(float4*)&cv[0] = *(const float4*)(C + s * HD + d0);
  *(float4*)&cv[4] = *(const float4*)(C + s * HD + d0 + 4);
  *(float4*)&sv[0] = *(const float4*)(Sn + s * HD + d0);
  *(float4*)&sv[4] = *(const float4*)(Sn + s * HD + d0 + 4);
  float sgn = (d0 & 32) ? 1.f : -1.f;
  float sc = (comp == 0) ? QSCALE : 1.f;
  uint4 ov; u16* os = (u16*)&ov;
#pragma unroll
  for (int j = 0; j < 8; j++)
    os[j] = f2b(sc * (b2f(vs[j]) * cv[j] + sgn * b2f(ps[j]) * sv[j]));
  *(uint4*)((comp == 0 ? Qo : Ko) + oo) = ov;
}

// ------------- V transpose: [bh][s][d] -> Vt [bh][d][s'] (bf16) ------------
// Key order PERMUTED within each 64-key block so attn's PV B-operand maps
// lane-local P registers with ZERO cross-lane exchange:
//   store key s (bits s5..s0) at c = {s5, s3, s2, s4, s1, s0}.
__global__ __launch_bounds__(256) void vtrans_k(const u16* __restrict__ V,
                                                u16* __restrict__ Vt) {
  __shared__ u16 ld[64 * 72];
  int t = threadIdx.x;
  int bh = blockIdx.x >> 5;          // 32 s-tiles per bh
  int s0 = (blockIdx.x & 31) * 64;
  const u16* src = V + (size_t)bh * SEQ * HD + (size_t)s0 * HD;
  u16* dst = Vt + (size_t)bh * SEQ * HD;
#pragma unroll
  for (int i = 0; i < 2; i++) {
    int c = t + i * 256, s = c >> 3, cp = c & 7;
    *(uint4*)&ld[s * 72 + ((cp ^ (s >> 3)) << 3)] =
        *(const uint4*)(src + (size_t)s * HD + cp * 8);
  }
  __syncthreads();
#pragma unroll
  for (int i = 0; i < 2; i++) {
    int c = t + i * 256, d = c >> 3, sc = c & 7;   // sc = s5s4s3 of local key
    u16 os[8];
#pragma unroll
    for (int j = 0; j < 8; j++) {
      int s = sc * 8 + j;
      os[j] = ld[s * 72 + (((d >> 3) ^ (s >> 3)) << 3) + (d & 7)];
    }
    // c(s) = 32*s5 + 16*s3 + 8*s2 + 4*s4 + s1s0
    int cb = ((sc >> 2) << 5) + ((sc & 1) << 4) + (((sc >> 1) & 1) << 2);
    *(uint2*)(dst + (size_t)d * SEQ + s0 + cb)     = *(const uint2*)&os[0];
    *(uint2*)(dst + (size_t)d * SEQ + s0 + cb + 8) = *(const uint2*)&os[4];
  }
}

// ------------ flash attention, swapped-QK in-register softmax --------------
// 8 waves, 128-row q tile, lane-local softmax (raw v_exp), chunk-XOR LDS
// swizzle (0 bank conflicts), key perm pre-baked into Vt.
// R16/R17: CROSS-TILE PIPELINE (T15-class). Per iteration:
//   stage(i+1) -> barrier -> QK(i+1) [MFMA] || softmax(i) [VALU] -> PV(i)
// QK(i+1) independent of softmax(i) -> VALU burst overlaps next tile's MFMA
// burst. K/V TRIPLE-buffered (R17: 64KB LDS total, down from R16's 80KB --
// removes the >64KB/block edge case; hazard still safe): buffer of tile t
// is rewritten at iter t+2 step1, AFTER barrier(t+1); last read is PV(t) at
// iter t step5, BEFORE that wave enters barrier(t+1) -> one barrier apart.
// One __syncthreads per tile. 2 blocks/CU (grid-limited at 512 blocks).
__global__ __launch_bounds__(512, 4) void attn_flash_k(const u16* __restrict__ Qg,
    const u16* __restrict__ Kg, const u16* __restrict__ Vtg, u16* __restrict__ Og) {
  __shared__ __align__(16) u16 q_s[128 * 64];     // Q staging (XOR-swizzled)
  __shared__ __align__(16) u16 k_s[3][64 * 64];   // K rows, triple-buffered
  __shared__ __align__(16) u16 vt_s[3][64 * 64];  // V^T rows (key-permuted)
  int t = threadIdx.x, lane = t & 63, w = t >> 6;   // w in 0..7
  int l15 = lane & 15, quad = lane >> 4;
  int lid = blockIdx.x;                      // 512 blocks
  int nid = (lid & 7) * 64 + (lid >> 3);     // XCD-contiguous remap
  int bh = nid >> 4;                         // 16 q-tiles per (b,h)
  int qt0 = (nid & 15) * 128;
  int b = bh >> 3, h = bh & 7;
  const u16* Qp = Qg + (size_t)bh * SEQ * HD;
  const u16* Kp = Kg + (size_t)bh * SEQ * HD;
  const u16* Vp = Vtg + (size_t)bh * SEQ * HD;   // [d][s'] permuted
  int row = t >> 3, ch = t & 7;    // staging: K -> row=key, V^T -> row=d
  int schu = (ch ^ (row & 7)) << 3;            // swizzled staging slot
  int r7 = l15 & 7;                            // read-side row bits

  // stage Q tile (128 rows, swizzled)
#pragma unroll
  for (int i = 0; i < 2; i++) {
    int c = t + i * 512, qr = c >> 3, qc = c & 7;
    *(uint4*)&q_s[qr * 64 + ((qc ^ (qr & 7)) << 3)] =
        *(const uint4*)(Qp + (size_t)(qt0 + qr) * HD + qc * 8);
  }
  // stage K/V tile 0 into buf0, issue tile 1 loads
  uint4 kr = *(const uint4*)(Kp + (size_t)row * HD + ch * 8);
  uint4 vr = *(const uint4*)(Vp + (size_t)row * SEQ + ch * 8);
  *(uint4*)&k_s[0][row * 64 + schu] = kr;
  *(uint4*)&vt_s[0][row * 64 + schu] = vr;
  kr = *(const uint4*)(Kp + (size_t)(64 + row) * HD + ch * 8);
  vr = *(const uint4*)(Vp + (size_t)row * SEQ + 64 + ch * 8);
  __syncthreads();                 // Q + tile0 visible
  bf16x8 qa[2];
  qa[0] = *(const bf16x8*)&q_s[(w * 16 + l15) * 64 + ((quad ^ r7) << 3)];
  qa[1] = *(const bf16x8*)&q_s[(w * 16 + l15) * 64 + (((4 + quad) ^ r7) << 3)];
  f32x4 z4 = {0.f, 0.f, 0.f, 0.f};
  f32x4 of[4];                     // of[nd][r] = O^T[d=nd*16+quad*4+r][q]
#pragma unroll
  for (int n = 0; n < 4; n++) of[n] = z4;
  float lrun = 0.f;                // one query per lane -> scalar sum

  // prologue: QK(0) from buf0
  f32x4 sf[4];
#pragma unroll
  for (int n = 0; n < 4; n++) sf[n] = z4;
  __builtin_amdgcn_s_setprio(1);
#pragma unroll
  for (int kk = 0; kk < 2; kk++)
#pragma unroll
    for (int n = 0; n < 4; n++) {
      bf16x8 kb = *(const bf16x8*)&k_s[0][(n * 16 + l15) * 64 +
                                         (((kk * 4 + quad) ^ r7) << 3)];
      sf[n] = __builtin_amdgcn_mfma_f32_16x16x32_bf16(kb, qa[kk], sf[n], 0, 0, 0);
    }
  __builtin_amdgcn_s_setprio(0);

  constexpr int NT = SEQ / 64;     // 32 tiles
  int bc = 0, bn = 1;              // buffer of tile i / tile i+1 (mod 3)
  for (int i = 0; i < NT; i++) {
    // stage tile i+1 into buf[bn]; issue tile i+2 loads
    if (i < NT - 1) {
      *(uint4*)&k_s[bn][row * 64 + schu] = kr;
      *(uint4*)&vt_s[bn][row * 64 + schu] = vr;
      if (i < NT - 2) {
        kr = *(const uint4*)(Kp + (size_t)((i + 2) * 64 + row) * HD + ch * 8);
        vr = *(const uint4*)(Vp + (size_t)row * SEQ + (i + 2) * 64 + ch * 8);
      }
    }
    __syncthreads();               // tile i+1 visible; single barrier per tile
    // QK(i+1) -> sfn (MFMA, independent of softmax(i))
    f32x4 sfn[4];
#pragma unroll
    for (int n = 0; n < 4; n++) sfn[n] = z4;
    if (i < NT - 1) {
      __builtin_amdgcn_s_setprio(1);
#pragma unroll
      for (int kk = 0; kk < 2; kk++)
#pragma unroll
        for (int n = 0; n < 4; n++) {
          bf16x8 kb = *(const bf16x8*)&k_s[bn][(n * 16 + l15) * 64 +
                                              (((kk * 4 + quad) ^ r7) << 3)];
          sfn[n] = __builtin_amdgcn_mfma_f32_16x16x32_bf16(kb, qa[kk], sfn[n], 0, 0, 0);
        }
      __builtin_amdgcn_s_setprio(0);
    }
    // softmax(i): raw v_exp_f32 (Q carried log2e/8), pack bf16 pairs
    u32 p32[8];                    // pbv(kk) = p32[4kk..4kk+3]
#pragma unroll
    for (int n = 0; n < 4; n++) {
      float e0 = __builtin_amdgcn_exp2f(sf[n][0]);
      float e1 = __builtin_amdgcn_exp2f(sf[n][1]);
      float e2 = __builtin_amdgcn_exp2f(sf[n][2]);
      float e3 = __builtin_amdgcn_exp2f(sf[n][3]);
      lrun += (e0 + e1) + (e2 + e3);
      asm("v_cvt_pk_bf16_f32 %0, %1, %2" : "=v"(p32[n * 2])     : "v"(e0), "v"(e1));
      asm("v_cvt_pk_bf16_f32 %0, %1, %2" : "=v"(p32[n * 2 + 1]) : "v"(e2), "v"(e3));
    }
    // PV(i): O^T += V^T P^T from buf[bc]
    __builtin_amdgcn_s_setprio(1);
#pragma unroll
    for (int kk = 0; kk < 2; kk++) {
      bf16x8 pbv;
      __builtin_memcpy(&pbv, &p32[kk * 4], 16);
#pragma unroll
      for (int nd = 0; nd < 4; nd++) {
        bf16x8 va = *(const bf16x8*)&vt_s[bc][(nd * 16 + l15) * 64 +
                                             (((kk * 4 + quad) ^ r7) << 3)];
        of[nd] = __builtin_amdgcn_mfma_f32_16x16x32_bf16(va, pbv, of[nd], 0, 0, 0);
      }
    }
    __builtin_amdgcn_s_setprio(0);
#pragma unroll
    for (int n = 0; n < 4; n++) sf[n] = sfn[n];
    bc = bn;
    bn = (bn == 2) ? 0 : bn + 1;
  }
  // norm: lane's partial covers its quad's keys; sum across quads (xor 16,32)
  float l = lrun;
  l += __shfl_xor(l, 16);
  l += __shfl_xor(l, 32);
  float inv = 1.f / l;
  size_t orow = (size_t)(b * SEQ + qt0 + w * 16 + l15);
#pragma unroll
  for (int nd = 0; nd < 4; nd++) {
    uint2 uv;
    uv.x = (u32)f2b(of[nd][0] * inv) | ((u32)f2b(of[nd][1] * inv) << 16);
    uv.y = (u32)f2b(of[nd][2] * inv) | ((u32)f2b(of[nd][3] * inv) << 16);
    *(uint2*)&Og[orow * DIMM + h * HD + nd * 16 + quad * 4] = uv;
  }
}

// ---------------------------------------------------------------------------
extern "C" void kernel_launch(void* const* d_in, const int* in_sizes, int n_in,
                              void* d_out, int out_size, void* d_ws, size_t ws_size,
                              hipStream_t stream) {
  const float* x    = (const float*)d_in[0];
  const float* rc   = (const float*)d_in[1];
  const float* rsn  = (const float*)d_in[2];
  const float* n1g  = (const float*)d_in[3];
  const float* n1b  = (const float*)d_in[4];
  const float* n2g  = (const float*)d_in[5];
  const float* n2b  = (const float*)d_in[6];
  const float* wqkv = (const float*)d_in[7];
  const float* bqkv = (const float*)d_in[8];
  const float* wprj = (const float*)d_in[9];
  const float* bprj = (const float*)d_in[10];
  const float* wf1  = (const float*)d_in[11];
  const float* bf1  = (const float*)d_in[12];
  const float* wf2  = (const float*)d_in[13];
  const float* bf2  = (const float*)d_in[14];

  char* p = (char*)d_ws;
  u16*   wqkvT = (u16*)p;                   // 1.5 MB
  u16*   wprjT = (u16*)(p + (2u  << 20));   // 0.5 MB
  u16*   wf1T  = (u16*)(p + (3u  << 20));   // 2 MB
  u16*   wf2T  = (u16*)(p + (5u  << 20));   // 2 MB
  u16*   h1    = (u16*)(p + (8u  << 20));   // 8 MB bf16: LN1 out / ob / h2
  u16*   qkvb  = (u16*)(p + (16u << 20));   // 24 MB bf16
  u16*   Vt    = (u16*)(p + (40u << 20));   // 8 MB bf16 (dead before FC1's mid)
  u16*   Qb    = (u16*)(p + (64u << 20));   // 8 MB bf16
  u16*   Kb    = (u16*)(p + (72u << 20));   // 8 MB bf16
  u16*   Vb    = (u16*)(p + (80u << 20));   // 8 MB bf16
  float* x2    = (float*)(p + (88u << 20)); // 16 MB f32 residual stream
  u16*   ob    = h1;                        // h1 dead after QKV gemm
  u16*   h2    = h1;                        // ob dead after proj gemm
  u16*   mid   = qkvb;                      // 32 MB bf16 region (qkvb+Vt dead)

  transpose_all_k<<<dim3((SZ_QKV + SZ_PRJ + SZ_F1 + SZ_F2) / 256), 256, 0, stream>>>(
      wqkv, wprj, wf1, wf2, wqkvT, wprjT, wf1T, wf2T);

  ln_f32b_k<<<dim3(BS / 4), 256, 0, stream>>>(x, n1g, n1b, h1);

  gemm_bt<3, 64, 128, 32><<<dim3(NQKV / 128, BS / 64), 256, 0, stream>>>(h1, wqkvT, bqkv, qkvb, nullptr, NQKV, DIMM);

  rope_k<<<dim3(BS * NQKV / 8 / 256), 256, 0, stream>>>(qkvb, rc, rsn, Qb, Kb, Vb);

  vtrans_k<<<dim3(32 * (SEQ / 64)), 256, 0, stream>>>(Vb, Vt);

  attn_flash_k<<<dim3(32 * (SEQ / 128)), 512, 0, stream>>>(Qb, Kb, Vt, ob);

  gemm_bt<1, 64, 64, 64><<<dim3(DIMM / 64, BS / 64), 256, 0, stream>>>(ob, wprjT, bprj, x2, x, DIMM, DIMM);

  ln_f32b_k<<<dim3(BS / 4), 256, 0, stream>>>(x2, n2g, n2b, h2);

  gemm_bt<2, 64, 128, 32><<<dim3(DFF / 128, BS / 64), 256, 0, stream>>>(h2, wf1T, bf1, mid, nullptr, DFF, DIMM);

  gemm_bt<1, 64, 64, 64><<<dim3(DIMM / 64, BS / 64), 256, 0, stream>>>(mid, wf2T, bf2, (float*)d_out, x2, DIMM, DFF);
}